// Round 12
// baseline (958.506 us; speedup 1.0000x reference)
//
#include <hip/hip_runtime.h>
#include <math.h>

#define DEV_INLINE __device__ __forceinline__

constexpr int H      = 256;
constexpr int NE     = 20000;
constexpr int NR     = 250;
constexpr int R2     = 500;
constexpr int TT     = 3;
constexpr int NEDGE  = 150000;
constexpr int M      = 200000;
constexpr int NNZ_E  = 320000;
constexpr int NNZ_R  = 8000;
constexpr int CH     = 50;
constexpr int NT     = 2000;
constexpr int NT2    = 4000;
constexpr int H3     = 3 * H;     // 768
constexpr int KFC    = CH * H;    // 12800
constexpr int ROWPAD = 4096;
constexpr int NCHUNK = 32;        // scores col chunks (x 10 panels x 64 cols)
constexpr int MSPLIT = 8;         // gather_mean row split
constexpr int FSPLIT = 20;        // fc split-K (640 = 10*64 per split)
constexpr int NB_CS  = 64;        // counting-sort blocks per R2 array
constexpr int NEPAD  = 20480;     // ent rows padded to 64
constexpr int NB_NE  = 80;        // NE-scan blocks per array
constexpr float PADCOLS = 480.f;  // NEPAD - NE: exp2(0) contributions to subtract

// cnt/start/cursor packed region (ints)
constexpr int CNT_NE_BASE   = 2048;
constexpr int CNT_NE_STRIDE = 20224;
constexpr int CNT_TOTAL     = CNT_NE_BASE + 4 * CNT_NE_STRIDE;  // 82944

typedef __bf16 bf16x8 __attribute__((ext_vector_type(8)));
typedef float  f32x4  __attribute__((ext_vector_type(4)));

DEV_INLINE bf16x8 ldb8(const __bf16* p) { return *(const bf16x8*)p; }
DEV_INLINE bf16x8 zerob8() { uint4 z = make_uint4(0, 0, 0, 0); return __builtin_bit_cast(bf16x8, z); }
DEV_INLINE f32x4 mfma16(bf16x8 a, bf16x8 b, f32x4 c) {
  return __builtin_amdgcn_mfma_f32_16x16x32_bf16(a, b, c, 0, 0, 0);
}
DEV_INLINE void gload_lds16(const void* g, void* l) {
  __builtin_amdgcn_global_load_lds((const __attribute__((address_space(1))) void*)g,
                                   (__attribute__((address_space(3))) void*)l, 16, 0, 0);
}

// ------------------------- block reduction (blockDim == 256) ---------------
DEV_INLINE float block_sum256(float v) {
  __shared__ float ws[4];
  #pragma unroll
  for (int o = 32; o > 0; o >>= 1) v += __shfl_down(v, o, 64);
  if ((threadIdx.x & 63) == 0) ws[threadIdx.x >> 6] = v;
  __syncthreads();
  float r = ws[0] + ws[1] + ws[2] + ws[3];
  __syncthreads();
  return r;
}

// ------------------- counting-sort CSR (R2-keyed arrays) -------------------
__global__ void cs_hist_k(const int* __restrict__ r_ids, const int* __restrict__ hr_row,
                          int* __restrict__ bcnt)
{
  __shared__ int lh[512];
  int a = blockIdx.y;
  const int* keys = (a < 3) ? r_ids + (size_t)a * M : hr_row;
  int n = (a < 3) ? M : NNZ_R;
  int t = threadIdx.x;
  lh[t] = 0; lh[t + 256] = 0;
  __syncthreads();
  int chunk = (n + NB_CS - 1) / NB_CS;
  int i0 = blockIdx.x * chunk, i1 = min(i0 + chunk, n);
  for (int i = i0 + t; i < i1; i += 256) atomicAdd(&lh[keys[i]], 1);
  __syncthreads();
  int* outp = bcnt + ((size_t)a * NB_CS + blockIdx.x) * 512;
  outp[t] = lh[t]; outp[t + 256] = lh[t + 256];
}

__global__ void cs_scan_k(const int* __restrict__ bcnt, int* __restrict__ bbase,
                          int* __restrict__ start_all)
{
  __shared__ int ps[257];
  int a = blockIdx.x;
  int* start = start_all + ((a < 3) ? a * 512 : 1536);
  const int* bc = bcnt + (size_t)a * NB_CS * 512;
  int* bb = bbase + (size_t)a * NB_CS * 512;
  int t = threadIdx.x;
  int b0 = 2 * t, b1 = 2 * t + 1;
  int tot0 = 0, tot1 = 0;
  for (int blk = 0; blk < NB_CS; blk++) {
    tot0 += bc[blk * 512 + b0];
    tot1 += bc[blk * 512 + b1];
  }
  ps[t + 1] = tot0 + tot1;
  if (t == 0) ps[0] = 0;
  __syncthreads();
  if (t == 0) { for (int i = 1; i <= 256; i++) ps[i] += ps[i - 1]; }
  __syncthreads();
  int run0 = ps[t], run1 = ps[t] + tot0;
  start[b0] = run0;
  start[b1] = run1;
  for (int blk = 0; blk < NB_CS; blk++) {
    bb[blk * 512 + b0] = run0; run0 += bc[blk * 512 + b0];
    bb[blk * 512 + b1] = run1; run1 += bc[blk * 512 + b1];
  }
}

__global__ void cs_scatter_k(const int* __restrict__ r_ids, const int* __restrict__ r_to_e,
                             const int* __restrict__ hr_row, const int* __restrict__ hr_col,
                             const float* __restrict__ hrv, const int* __restrict__ bbase,
                             int* __restrict__ f0, int* __restrict__ f1, int* __restrict__ f2,
                             int2* __restrict__ fcvHR)
{
  __shared__ int cur[512];
  int a = blockIdx.y;
  const int* keys = (a < 3) ? r_ids + (size_t)a * M : hr_row;
  int n = (a < 3) ? M : NNZ_R;
  int t = threadIdx.x;
  const int* bb = bbase + ((size_t)a * NB_CS + blockIdx.x) * 512;
  cur[t] = bb[t]; cur[t + 256] = bb[t + 256];
  __syncthreads();
  int chunk = (n + NB_CS - 1) / NB_CS;
  int i0 = blockIdx.x * chunk, i1 = min(i0 + chunk, n);
  if (a < 3) {
    const int* other = r_to_e + (size_t)a * M;
    int* f = (a == 0) ? f0 : (a == 1) ? f1 : f2;
    for (int i = i0 + t; i < i1; i += 256) {
      int p = atomicAdd(&cur[keys[i]], 1);
      f[p] = other[i];
    }
  } else {
    for (int i = i0 + t; i < i1; i += 256) {
      int p = atomicAdd(&cur[keys[i]], 1);
      fcvHR[p] = make_int2(hr_col[i], __float_as_int(hrv[i]));
    }
  }
}

// ------------------- NE-keyed CSR (low contention) -------------------------
__global__ void hist_ne_k(const int* __restrict__ edge_dst, const int* __restrict__ he_row,
                          int* __restrict__ cnt_all)
{
  int a = blockIdx.y;
  const int* keys = (a < 3) ? edge_dst + (size_t)a * NEDGE : he_row;
  int n = (a < 3) ? NEDGE : NNZ_E;
  int* cnt = cnt_all + CNT_NE_BASE + a * CNT_NE_STRIDE;
  int i = blockIdx.x * 256 + threadIdx.x;
  if (i < n) atomicAdd(&cnt[keys[i]], 1);
}

__global__ void scan_ne1_k(const int* __restrict__ cnt_all, int* __restrict__ start_all,
                           int* __restrict__ bsum)
{
  __shared__ int wtot[4];
  int a = blockIdx.y;
  int off = CNT_NE_BASE + a * CNT_NE_STRIDE;
  int bin = blockIdx.x * 256 + threadIdx.x;
  int lane = threadIdx.x & 63, w = threadIdx.x >> 6;
  int v = (bin < NE) ? cnt_all[off + bin] : 0;
  int orig = v;
  #pragma unroll
  for (int o = 1; o < 64; o <<= 1) {
    int n = __shfl_up(v, o, 64);
    if (lane >= o) v += n;
  }
  if (lane == 63) wtot[w] = v;
  __syncthreads();
  int wo = 0;
  #pragma unroll
  for (int i = 0; i < 4; i++) if (i < w) wo += wtot[i];
  if (bin < NE) start_all[off + bin] = v - orig + wo;
  if (threadIdx.x == 255) bsum[a * NB_NE + blockIdx.x] = wo + v;
}

__global__ void scan_ne2_k(int* __restrict__ bsum, int* __restrict__ start_all)
{
  __shared__ int s[NB_NE + 1];
  int a = blockIdx.x;
  int t = threadIdx.x;
  if (t < NB_NE) s[t + 1] = bsum[a * NB_NE + t];
  if (t == 0) s[0] = 0;
  __syncthreads();
  if (t == 0) { for (int i = 1; i <= NB_NE; i++) s[i] += s[i - 1]; }
  __syncthreads();
  if (t < NB_NE) bsum[a * NB_NE + t] = s[t];
  if (t == 0) start_all[CNT_NE_BASE + a * CNT_NE_STRIDE + NE] = s[NB_NE];
}

__global__ void scan_ne3_k(int* __restrict__ start_all, int* __restrict__ cursor_all,
                           const int* __restrict__ bsum)
{
  int a = blockIdx.y;
  int off = CNT_NE_BASE + a * CNT_NE_STRIDE;
  int bin = blockIdx.x * 256 + threadIdx.x;
  if (bin >= NE) return;
  int v = start_all[off + bin] + bsum[a * NB_NE + blockIdx.x];
  start_all[off + bin] = v;
  cursor_all[off + bin] = v;
}

// batched: 3 edge arrays in one launch (grid.y = 3)
__global__ void perm_fuse2i_k(const int* __restrict__ edge_dst, const int* __restrict__ edge_src,
                              const int* __restrict__ edge_rel, int* __restrict__ cursor_all,
                              int2* __restrict__ f0, int2* __restrict__ f1, int2* __restrict__ f2)
{
  int a = blockIdx.y;
  const int* keys = edge_dst + (size_t)a * NEDGE;
  const int* o1 = edge_src + (size_t)a * NEDGE;
  const int* o2 = edge_rel + (size_t)a * NEDGE;
  int* cursor = cursor_all + CNT_NE_BASE + a * CNT_NE_STRIDE;
  int2* f = (a == 0) ? f0 : (a == 1) ? f1 : f2;
  int i = blockIdx.x * 256 + threadIdx.x;
  if (i < NEDGE) { int p = atomicAdd(&cursor[keys[i]], 1); f[p] = make_int2(o1[i], o2[i]); }
}
__global__ void perm_fusevi_k(const int* __restrict__ keys, const int* __restrict__ col,
                              const float* __restrict__ val, int n, int* __restrict__ cursor,
                              int2* __restrict__ f)
{
  int i = blockIdx.x * 256 + threadIdx.x;
  if (i < n) {
    int p = atomicAdd(&cursor[keys[i]], 1);
    f[p] = make_int2(col[i], __float_as_int(val[i]));
  }
}

// ------------------------- casts / transposes ------------------------------
__global__ void cast_bf16_k(const float* __restrict__ in, __bf16* __restrict__ out, int n8)
{
  int i = blockIdx.x * 256 + threadIdx.x;
  if (i >= n8) return;
  const float4* p = (const float4*)in + (size_t)i * 2;
  float4 u = p[0], v = p[1];
  bf16x8 o;
  o[0] = (__bf16)u.x; o[1] = (__bf16)u.y; o[2] = (__bf16)u.z; o[3] = (__bf16)u.w;
  o[4] = (__bf16)v.x; o[5] = (__bf16)v.y; o[6] = (__bf16)v.z; o[7] = (__bf16)v.w;
  ((bf16x8*)out)[i] = o;
}

// copy fp32 + emit bf16 in one pass
__global__ void copy_cast_k(const float* __restrict__ in, float* __restrict__ outf,
                            __bf16* __restrict__ outb, int n8)
{
  int i = blockIdx.x * 256 + threadIdx.x;
  if (i >= n8) return;
  const float4* p = (const float4*)in + (size_t)i * 2;
  float4 u = p[0], v = p[1];
  ((float4*)outf)[(size_t)i * 2]     = u;
  ((float4*)outf)[(size_t)i * 2 + 1] = v;
  bf16x8 o;
  o[0] = (__bf16)u.x; o[1] = (__bf16)u.y; o[2] = (__bf16)u.z; o[3] = (__bf16)u.w;
  o[4] = (__bf16)v.x; o[5] = (__bf16)v.y; o[6] = (__bf16)v.z; o[7] = (__bf16)v.w;
  ((bf16x8*)outb)[i] = o;
}

__global__ void transpose_cast_k(const float* __restrict__ in, __bf16* __restrict__ out,
                                 int K, int N)
{
  __shared__ float tile[32][33];
  int tx = threadIdx.x & 31, ty = threadIdx.x >> 5;   // 32 x 8
  int kb = blockIdx.x * 32, nb = blockIdx.y * 32;
  #pragma unroll
  for (int i = 0; i < 4; i++)
    tile[ty + i * 8][tx] = in[(size_t)(kb + ty + i * 8) * N + nb + tx];
  __syncthreads();
  #pragma unroll
  for (int i = 0; i < 4; i++)
    out[(size_t)(nb + ty + i * 8) * K + kb + tx] = (__bf16)tile[tx][ty + i * 8];
}

// reorder [rows][256] bf16 into MFMA-frag-linear layout
__global__ void pack_frag_k(const __bf16* __restrict__ src, __bf16* __restrict__ dst,
                            int nchunks, int Mr)
{
  int i = blockIdx.x * 256 + threadIdx.x;
  if (i >= nchunks) return;
  int c = i >> 5, s = i & 31;
  bf16x8 v = (c < Mr) ? ldb8(src + (size_t)c * H + s * 8) : zerob8();
  int kf = s >> 2, kg = s & 3;
  size_t d = ((((size_t)(c >> 6) * 4 + ((c >> 4) & 3)) * 8 + kf) * 4 + kg) * 16 + (c & 15);
  *(bf16x8*)(dst + d * 8) = v;
}

// ------------------------- gather kernels (16 B/lane, 32-lane halves) ------
__global__ void gather_mean2_k(const __bf16* __restrict__ src, const int* __restrict__ fidx,
                               const int* __restrict__ start, float* __restrict__ part)
{
  __shared__ __align__(16) float red[4][H];
  int r = blockIdx.x, s = blockIdx.y;
  int s0 = start[r], s1 = start[r + 1];
  int len = s1 - s0;
  int chunk = (len + MSPLIT - 1) / MSPLIT;
  int jb = s0 + s * chunk, je = min(jb + chunk, s1);
  int tid = threadIdx.x, lane = tid & 63, w = tid >> 6;
  int half = lane >> 5, l = lane & 31;
  float acc[8] = {0.f, 0.f, 0.f, 0.f, 0.f, 0.f, 0.f, 0.f};
  for (int j = jb + w * 2 + half; j < je; j += 8) {
    int e = fidx[j];
    bf16x8 v = ldb8(src + (size_t)e * H + l * 8);
    #pragma unroll
    for (int q = 0; q < 8; q++) acc[q] += (float)v[q];
  }
  #pragma unroll
  for (int q = 0; q < 8; q++) acc[q] += __shfl_xor(acc[q], 32, 64);
  if (half == 0) {
    *(float4*)&red[w][l * 8]     = make_float4(acc[0], acc[1], acc[2], acc[3]);
    *(float4*)&red[w][l * 8 + 4] = make_float4(acc[4], acc[5], acc[6], acc[7]);
  }
  __syncthreads();
  int h = tid;
  part[((size_t)r * MSPLIT + s) * H + h] = red[0][h] + red[1][h] + red[2][h] + red[3][h];
}

__global__ void mean_xin_k(const float* __restrict__ partM, const int* __restrict__ start,
                           const float* __restrict__ rel, __bf16* __restrict__ xin)
{
  int r = blockIdx.x, h = threadIdx.x;
  float s = 0.f;
  #pragma unroll
  for (int z = 0; z < MSPLIT; z++) s += partM[((size_t)r * MSPLIT + z) * H + h];
  float xm = s / (float)max(start[r + 1] - start[r], 1);
  xin[(size_t)r * 2 * H + h]     = (__bf16)rel[(size_t)r * H + h];
  xin[(size_t)r * 2 * H + H + h] = (__bf16)xm;
}

__global__ void gather_edges3_k(const __bf16* __restrict__ ent, const __bf16* __restrict__ rel,
                                const int2* __restrict__ fsr,
                                const int* __restrict__ start, __bf16* __restrict__ out)
{
  __shared__ __align__(16) float red[4][H];
  int d = blockIdx.x;
  int s0 = start[d], s1 = start[d + 1];
  int tid = threadIdx.x, lane = tid & 63, w = tid >> 6;
  int half = lane >> 5, l = lane & 31;
  const __bf16* srcbase = half ? rel : ent;
  float acc[8] = {0.f, 0.f, 0.f, 0.f, 0.f, 0.f, 0.f, 0.f};
  for (int j = s0 + w; j < s1; j += 4) {
    int2 e2 = fsr[j];
    int e = half ? e2.y : e2.x;
    bf16x8 v = ldb8(srcbase + (size_t)e * H + l * 8);
    #pragma unroll
    for (int q = 0; q < 8; q++) acc[q] += (float)v[q];
  }
  #pragma unroll
  for (int q = 0; q < 8; q++) acc[q] += __shfl_xor(acc[q], 32, 64);
  if (half == 0) {
    *(float4*)&red[w][l * 8]     = make_float4(acc[0], acc[1], acc[2], acc[3]);
    *(float4*)&red[w][l * 8 + 4] = make_float4(acc[4], acc[5], acc[6], acc[7]);
  }
  __syncthreads();
  int h = tid;
  float sum = red[0][h] + red[1][h] + red[2][h] + red[3][h];
  out[(size_t)d * H + h] = (__bf16)(sum / (float)max(s1 - s0, 1));
}

__global__ void hyper3_k(const float* __restrict__ x, const __bf16* __restrict__ xb,
                         const int2* __restrict__ fcv,
                         const int* __restrict__ start,
                         float* __restrict__ xout, __bf16* __restrict__ xoutb)
{
  __shared__ __align__(16) float red[4][H];
  int r = blockIdx.x;
  int s0 = start[r], s1 = start[r + 1];
  int tid = threadIdx.x, lane = tid & 63, w = tid >> 6;
  int half = lane >> 5, l = lane & 31;
  float acc[8] = {0.f, 0.f, 0.f, 0.f, 0.f, 0.f, 0.f, 0.f};
  for (int j = s0 + w * 2 + half; j < s1; j += 8) {
    int2 cv = fcv[j];
    float wt = __int_as_float(cv.y);
    bf16x8 v = ldb8(xb + (size_t)cv.x * H + l * 8);
    #pragma unroll
    for (int q = 0; q < 8; q++) acc[q] += wt * (float)v[q];
  }
  #pragma unroll
  for (int q = 0; q < 8; q++) acc[q] += __shfl_xor(acc[q], 32, 64);
  if (half == 0) {
    *(float4*)&red[w][l * 8]     = make_float4(acc[0], acc[1], acc[2], acc[3]);
    *(float4*)&red[w][l * 8 + 4] = make_float4(acc[4], acc[5], acc[6], acc[7]);
  }
  __syncthreads();
  int h = tid;
  float y = red[0][h] + red[1][h] + red[2][h] + red[3][h];
  float ss = block_sum256(y * y);
  float rn = 1.f / fmaxf(sqrtf(ss), 1e-12f);
  float o = x[(size_t)r * H + h] + y * rn;
  xout[(size_t)r * H + h] = o;
  xoutb[(size_t)r * H + h] = (__bf16)o;
}

__global__ void hyper_rel_k(const float* __restrict__ x, const int2* __restrict__ fcv,
                            const int* __restrict__ start, float* __restrict__ xout)
{
  int r = blockIdx.x, h = threadIdx.x;
  int s0 = start[r], s1 = start[r + 1];
  float a0 = 0.f;
  for (int j = s0; j < s1; j++) {
    int2 cv = fcv[j];
    a0 += __int_as_float(cv.y) * x[(size_t)cv.x * H + h];
  }
  float ss = block_sum256(a0 * a0);
  float rn = 1.f / fmaxf(sqrtf(ss), 1e-12f);
  xout[(size_t)r * H + h] = x[(size_t)r * H + h] + a0 * rn;
}

// ------------------------- small elementwise -------------------------------
__global__ void gru_combine(const float* __restrict__ gi, const float* __restrict__ gh,
                            float* __restrict__ rel, __bf16* __restrict__ relb)
{
  int idx = blockIdx.x * 256 + threadIdx.x;       // R2 * H
  if (idx >= R2 * H) return;
  int i = idx >> 8, h = idx & 255;
  const float* gir = gi + (size_t)i * H3;
  const float* ghr = gh + (size_t)i * H3;
  float r = 1.f / (1.f + __expf(-(gir[h]       + ghr[h])));
  float z = 1.f / (1.f + __expf(-(gir[H + h]   + ghr[H + h])));
  float n = tanhf(gir[2 * H + h] + r * ghr[2 * H + h]);
  float o = (1.f - z) * n + z * rel[idx];
  rel[idx] = o;
  relb[idx] = (__bf16)o;
}

// ------------------------- panel2 GEMM (K=256, dbuf 64-col B panels) --------
DEV_INLINE void stage64_load(uint4* v, const __bf16* src, int rowBase, int rowLimit, int tid)
{
  #pragma unroll
  for (int q = 0; q < 8; q++) {
    int X = (q * 256 + tid) * 16;
    int row = X >> 9, boff = X & 511;
    int grow = min(rowBase + row, rowLimit);
    v[q] = *(const uint4*)((const char*)src + (size_t)grow * 512 + boff);
  }
}
DEV_INLINE void stage64_write(char* lds, const uint4* v, int tid)
{
  #pragma unroll
  for (int q = 0; q < 8; q++) {
    int X = (q * 256 + tid) * 16;
    int row = X >> 9;
    *(uint4*)(lds + (X ^ ((row & 7) << 4))) = v[q];
  }
}
DEV_INLINE void stage32_load(uint4* v, const __bf16* src, int rowBase, int rowLimit, int tid, int hf)
{
  #pragma unroll
  for (int q = 0; q < 4; q++) {
    int X = ((hf * 4 + q) * 256 + tid) * 16;
    int row = X >> 9, boff = X & 511;
    int grow = min(rowBase + row, rowLimit);
    v[q] = *(const uint4*)((const char*)src + (size_t)grow * 512 + boff);
  }
}
DEV_INLINE void stage32_write(char* lds, const uint4* v, int tid, int hf)
{
  #pragma unroll
  for (int q = 0; q < 4; q++) {
    int X = ((hf * 4 + q) * 256 + tid) * 16;
    int row = X >> 9;
    *(uint4*)(lds + (X ^ ((row & 7) << 4))) = v[q];
  }
}
DEV_INLINE bf16x8 frag64(const char* lds, int row, int kf, int kg)
{
  int off = (kf * 64 + kg * 16) ^ ((row & 7) << 4);
  return *(const bf16x8*)(lds + row * 512 + off);
}

// EPI: 2 = bias+sigmoid store to out; 4 = relu + gate-blend, writes entf/entbo
template<int EPI>
__global__ __launch_bounds__(256, 2) void panel2_gemm(const __bf16* __restrict__ A,
                                                      const __bf16* __restrict__ B,
                                                      const float* __restrict__ bias,
                                                      float* __restrict__ out,
                                                      int Mr, int N, int PS,
                                                      const float* __restrict__ gate,
                                                      float* __restrict__ entf,
                                                      __bf16* __restrict__ entbo)
{
  __shared__ __attribute__((aligned(16))) char lds0[32768];
  __shared__ __attribute__((aligned(16))) char lds1[32768];
  int tid = threadIdx.x;
  int lane = tid & 63, wM = tid >> 6;
  int r = lane & 15, kg = lane >> 4;
  int rowBase = blockIdx.y * 128;

  {
    uint4 va[8];
    stage64_load(va, A, rowBase, Mr - 1, tid);
    stage64_write(lds0, va, tid);
    stage64_load(va, A, rowBase + 64, Mr - 1, tid);
    stage64_write(lds1, va, tid);
  }
  __syncthreads();

  bf16x8 a[2][8];
  {
    int base = wM * 32;
    const char* ab = (base >= 64) ? lds1 : lds0;
    #pragma unroll
    for (int i = 0; i < 2; i++) {
      int ar = (base + i * 16 + r) & 63;
      #pragma unroll
      for (int kf = 0; kf < 8; kf++) a[i][kf] = frag64(ab, ar, kf, kg);
    }
  }
  int p0 = blockIdx.x * PS;
  __syncthreads();
  {
    uint4 va[8];
    stage64_load(va, B, p0 * 64, N - 1, tid);
    stage64_write(lds0, va, tid);
  }
  __syncthreads();

  for (int p = 0; p < PS; p++) {
    char* cur = (p & 1) ? lds1 : lds0;
    char* nxt = (p & 1) ? lds0 : lds1;
    bool pre = (p + 1 < PS);
    uint4 v4[4];
    if (pre) stage32_load(v4, B, (p0 + p + 1) * 64, N - 1, tid, 0);

    f32x4 acc[2][4];
    #pragma unroll
    for (int i = 0; i < 2; i++)
      #pragma unroll
      for (int j = 0; j < 4; j++) {
        acc[i][j][0] = 0.f; acc[i][j][1] = 0.f; acc[i][j][2] = 0.f; acc[i][j][3] = 0.f;
      }
    __builtin_amdgcn_s_setprio(1);
    #pragma unroll
    for (int kf = 0; kf < 4; kf++) {
      bf16x8 b[4];
      #pragma unroll
      for (int j = 0; j < 4; j++) b[j] = frag64(cur, j * 16 + r, kf, kg);
      #pragma unroll
      for (int i = 0; i < 2; i++)
        #pragma unroll
        for (int j = 0; j < 4; j++)
          acc[i][j] = mfma16(a[i][kf], b[j], acc[i][j]);
    }
    __builtin_amdgcn_s_setprio(0);
    if (pre) {
      stage32_write(nxt, v4, tid, 0);
      stage32_load(v4, B, (p0 + p + 1) * 64, N - 1, tid, 1);
    }
    __builtin_amdgcn_s_setprio(1);
    #pragma unroll
    for (int kf = 4; kf < 8; kf++) {
      bf16x8 b[4];
      #pragma unroll
      for (int j = 0; j < 4; j++) b[j] = frag64(cur, j * 16 + r, kf, kg);
      #pragma unroll
      for (int i = 0; i < 2; i++)
        #pragma unroll
        for (int j = 0; j < 4; j++)
          acc[i][j] = mfma16(a[i][kf], b[j], acc[i][j]);
    }
    __builtin_amdgcn_s_setprio(0);
    if (pre) stage32_write(nxt, v4, tid, 1);

    #pragma unroll
    for (int i = 0; i < 2; i++)
      #pragma unroll
      for (int g = 0; g < 4; g++) {
        int row = rowBase + wM * 32 + i * 16 + kg * 4 + g;
        if (row >= Mr) continue;
        #pragma unroll
        for (int j = 0; j < 4; j++) {
          int col = (p0 + p) * 64 + j * 16 + r;
          if (col >= N) continue;
          float v = acc[i][j][g];
          if (EPI == 2) {
            if (bias) v += bias[col];
            v = 1.f / (1.f + __expf(-v));
            out[(size_t)row * N + col] = v;
          } else {   // EPI == 4: relu + gate blend + dual store
            v = fmaxf(v, 0.f);
            size_t idx = (size_t)row * N + col;
            float t = gate[idx];
            float o = t * v + (1.f - t) * entf[idx];
            entf[idx] = o;
            entbo[idx] = (__bf16)o;
          }
        }
      }
    __syncthreads();
  }
}

// ------------------------- scores_v3 (frag-packed, 64-row waves) -----------
__global__ __launch_bounds__(256, 2) void scores_v3(const __bf16* __restrict__ qbf,
                                                    const __bf16* __restrict__ ebf,
                                                    float* __restrict__ part_l)
{
  __shared__ __attribute__((aligned(16))) char lds[2][32768];
  int tid = threadIdx.x, lane = tid & 63, w = tid >> 6;
  int r = lane & 15, kg = lane >> 4;

  auto stage = [&](int buf, int p) {
    const char* g = (const char*)ebf + ((size_t)(blockIdx.x * 10 + p)) * 32768;
    int wbase = (tid & ~63) * 16;     // wave*1024
    #pragma unroll
    for (int q = 0; q < 8; q++) {
      int o = q * 4096 + wbase;
      gload_lds16(g + o + (lane * 16), lds[buf] + o);
    }
  };

  stage(0, 0);

  bf16x8 a[4][8];
  {
    const __bf16* ap = qbf + ((size_t)(blockIdx.y * 4 + w)) * 16384 + kg * 128 + r * 8;
    #pragma unroll
    for (int i = 0; i < 4; i++)
      #pragma unroll
      for (int kf = 0; kf < 8; kf++)
        a[i][kf] = ldb8(ap + (i * 8 + kf) * 512);
  }
  __syncthreads();

  float lsum[4][4];
  #pragma unroll
  for (int i = 0; i < 4; i++)
    #pragma unroll
    for (int g = 0; g < 4; g++) lsum[i][g] = 0.f;

  const char* lane_off0 = lds[0] + kg * 256 + r * 16;
  const char* lane_off1 = lds[1] + kg * 256 + r * 16;

  for (int p = 0; p < 10; p++) {
    if (p + 1 < 10) stage((p + 1) & 1, p + 1);
    const char* cur = (p & 1) ? lane_off1 : lane_off0;

    f32x4 acc[4][4];
    #pragma unroll
    for (int i = 0; i < 4; i++)
      #pragma unroll
      for (int j = 0; j < 4; j++) {
        acc[i][j][0] = 0.f; acc[i][j][1] = 0.f; acc[i][j][2] = 0.f; acc[i][j][3] = 0.f;
      }
    __builtin_amdgcn_s_setprio(1);
    #pragma unroll
    for (int kf = 0; kf < 8; kf++) {
      bf16x8 b[4];
      #pragma unroll
      for (int j = 0; j < 4; j++)
        b[j] = *(const bf16x8*)(cur + (j * 8 + kf) * 1024);
      #pragma unroll
      for (int i = 0; i < 4; i++)
        #pragma unroll
        for (int j = 0; j < 4; j++)
          acc[i][j] = mfma16(a[i][kf], b[j], acc[i][j]);
    }
    __builtin_amdgcn_s_setprio(0);

    // padded cols (>= NE) contribute exp2(0)=1 each; corrected in lse_combine
    #pragma unroll
    for (int j = 0; j < 4; j++)
      #pragma unroll
      for (int i = 0; i < 4; i++)
        #pragma unroll
        for (int g = 0; g < 4; g++)
          lsum[i][g] += exp2f(acc[i][j][g]);
    __syncthreads();
  }

  #pragma unroll
  for (int m = 1; m < 16; m <<= 1)
    #pragma unroll
    for (int i = 0; i < 4; i++)
      #pragma unroll
      for (int g = 0; g < 4; g++)
        lsum[i][g] += __shfl_xor(lsum[i][g], m, 64);
  if (r == 0) {
    #pragma unroll
    for (int i = 0; i < 4; i++)
      #pragma unroll
      for (int g = 0; g < 4; g++) {
        int row = blockIdx.y * 256 + w * 64 + i * 16 + kg * 4 + g;
        part_l[(size_t)blockIdx.x * ROWPAD + row] = lsum[i][g];
      }
  }
}

// ------------------------- fc GEMM (K = 12800, LDS-staged, split-K=20) -----
__global__ __launch_bounds__(256) void fc_gemm(const __bf16* __restrict__ A,
                                               const __bf16* __restrict__ Bt,
                                               float* __restrict__ part, int Mr)
{
  __shared__ __attribute__((aligned(16))) char lds[49152];
  int tid = threadIdx.x;
  int lane = tid & 63, wave = tid >> 6;
  int wM = wave >> 1, wN = wave & 1;
  int r = lane & 15, kg = lane >> 4;
  int rowBase = blockIdx.y * 128;
  int kbeg = blockIdx.x * (KFC / FSPLIT);   // 640

  f32x4 acc[4][8];
  #pragma unroll
  for (int i = 0; i < 4; i++)
    #pragma unroll
    for (int j = 0; j < 8; j++) {
      acc[i][j][0] = 0.f; acc[i][j][1] = 0.f; acc[i][j][2] = 0.f; acc[i][j][3] = 0.f;
    }

  for (int ks = 0; ks < KFC / FSPLIT / 64; ks++) {
    int kb = kbeg + ks * 64;
    #pragma unroll
    for (int q = 0; q < 12; q++) {
      int X = (q * 256 + tid) * 16;
      int row = X >> 7;
      int off = X & 127;
      int soff = off ^ ((row & 7) << 4);
      uint4 v;
      if (row < 128) {
        int grow = min(rowBase + row, Mr - 1);
        v = *(const uint4*)((const char*)A + (size_t)grow * (KFC * 2) + kb * 2 + soff);
      } else {
        int col = row - 128;
        v = *(const uint4*)((const char*)Bt + (size_t)col * (KFC * 2) + kb * 2 + soff);
      }
      *(uint4*)(lds + X) = v;
    }
    __syncthreads();
    #pragma unroll
    for (int kf = 0; kf < 2; kf++) {
      bf16x8 a[4], b[8];
      #pragma unroll
      for (int i = 0; i < 4; i++) {
        int row = wM * 64 + i * 16 + r;
        int off = (kf * 64 + kg * 16) ^ ((row & 7) << 4);
        a[i] = *(const bf16x8*)(lds + row * 128 + off);
      }
      #pragma unroll
      for (int j = 0; j < 8; j++) {
        int row = 128 + wN * 128 + j * 16 + r;
        int off = (kf * 64 + kg * 16) ^ ((row & 7) << 4);
        b[j] = *(const bf16x8*)(lds + row * 128 + off);
      }
      #pragma unroll
      for (int i = 0; i < 4; i++)
        #pragma unroll
        for (int j = 0; j < 8; j++)
          acc[i][j] = mfma16(a[i], b[j], acc[i][j]);
    }
    __syncthreads();
  }

  float* pz = part + (size_t)blockIdx.x * Mr * H;
  #pragma unroll
  for (int i = 0; i < 4; i++)
    #pragma unroll
    for (int g = 0; g < 4; g++) {
      int row = rowBase + wM * 64 + i * 16 + kg * 4 + g;
      if (row >= Mr) continue;
      #pragma unroll
      for (int j = 0; j < 8; j++) {
        int col = wN * 128 + j * 16 + r;
        pz[(size_t)row * H + col] = acc[i][j][g];
      }
    }
}

// ------------------------- GRU dual GEMM (z=0: gi, z=1: gh) ----------------
__global__ void gru_gemm2_k(const __bf16* __restrict__ xinb, const __bf16* __restrict__ relb,
                            const __bf16* __restrict__ Wihb, const __bf16* __restrict__ Whhb,
                            const float* __restrict__ b_ih, const float* __restrict__ b_hh,
                            float* __restrict__ gi, float* __restrict__ gh)
{
  const __bf16* A; const __bf16* Bt; const float* bias; float* C; int K;
  if (blockIdx.z == 0) { A = xinb; Bt = Wihb; bias = b_ih; C = gi; K = 2 * H; }
  else                 { A = relb; Bt = Whhb; bias = b_hh; C = gh; K = H; }
  const int Mr = R2, N = H3;

  int lane = threadIdx.x & 63, wave = threadIdx.x >> 6;
  int waveM = wave >> 1, waveN = wave & 1;
  int r = lane & 15, kg = lane >> 4;
  int rowBase = blockIdx.y * 64 + waveM * 32;
  int colBase = blockIdx.x * 64 + waveN * 32;

  int row0 = rowBase + r, row1 = rowBase + 16 + r;
  int col0 = colBase + r, col1 = colBase + 16 + r;
  bool v0 = row0 < Mr, v1 = row1 < Mr;
  const __bf16* a0p = A + (size_t)row0 * K + kg * 8;
  const __bf16* a1p = A + (size_t)row1 * K + kg * 8;
  const __bf16* b0p = Bt + (size_t)col0 * K + kg * 8;
  const __bf16* b1p = Bt + (size_t)col1 * K + kg * 8;

  f32x4 acc[2][2];
  #pragma unroll
  for (int i = 0; i < 2; i++)
    #pragma unroll
    for (int j = 0; j < 2; j++) { acc[i][j][0] = 0.f; acc[i][j][1] = 0.f; acc[i][j][2] = 0.f; acc[i][j][3] = 0.f; }

  for (int k0 = 0; k0 < K; k0 += 32) {
    bf16x8 a0 = v0 ? ldb8(a0p + k0) : zerob8();
    bf16x8 a1 = v1 ? ldb8(a1p + k0) : zerob8();
    bf16x8 b0 = ldb8(b0p + k0);
    bf16x8 b1 = ldb8(b1p + k0);
    acc[0][0] = mfma16(a0, b0, acc[0][0]);
    acc[0][1] = mfma16(a0, b1, acc[0][1]);
    acc[1][0] = mfma16(a1, b0, acc[1][0]);
    acc[1][1] = mfma16(a1, b1, acc[1][1]);
  }

  #pragma unroll
  for (int i = 0; i < 2; i++) {
    #pragma unroll
    for (int g = 0; g < 4; g++) {
      int row = rowBase + i * 16 + kg * 4 + g;
      if (row >= Mr) continue;
      #pragma unroll
      for (int j = 0; j < 2; j++) {
        int col = colBase + j * 16 + r;
        C[(size_t)row * N + col] = acc[i][j][g] + bias[col];
      }
    }
  }
}

// sum split-K partials + bias + relu -> q (fp32) and qb (bf16, prescaled log2 e)
__global__ void fc_reduce(const float* __restrict__ part, const float* __restrict__ bias,
                          float* __restrict__ q, __bf16* __restrict__ qb, int nrows)
{
  int idx = blockIdx.x * 256 + threadIdx.x;       // nrows * H
  if (idx >= nrows * H) return;
  int col = idx & 255;
  float s = bias[col];
  for (int z = 0; z < FSPLIT; z++) s += part[(size_t)z * nrows * H + idx];
  s = fmaxf(s, 0.f);
  q[idx] = s;
  qb[idx] = (__bf16)(s * 1.44269504f);
}

// ------------------------- conv (block per test row) -----------------------
__global__ void conv_feat(const float* __restrict__ ent, const float* __restrict__ rel,
                          const float* __restrict__ sent, const int* __restrict__ tt,
                          const float* __restrict__ cw, const float* __restrict__ cb,
                          __bf16* __restrict__ out, int row0)
{
  __shared__ float f[3][258];
  __shared__ float wsm[CH * 9];
  __shared__ float bsm[CH];
  int i = row0 + blockIdx.x;
  int h = threadIdx.x;
  int j = (i < NT) ? i : i - NT;
  int a0 = (i < NT) ? tt[j * 3 + 0] : tt[j * 3 + 2];
  int a1 = (i < NT) ? tt[j * 3 + 1] : tt[j * 3 + 1] + NR;
  f[0][h + 1] = ent[(size_t)a0 * H + h];
  f[1][h + 1] = rel[(size_t)a1 * H + h];
  f[2][h + 1] = sent[(size_t)j * H + h];
  if (h < 3) { f[h][0] = 0.f; f[h][257] = 0.f; }
  for (int x = h; x < CH * 9; x += 256) wsm[x] = cw[x];
  if (h < CH) bsm[h] = cb[h];
  __syncthreads();
  __bf16* orow = out + (size_t)blockIdx.x * KFC;
  for (int c = 0; c < CH; c++) {
    const float* wc = wsm + c * 9;
    float s = bsm[c];
    #pragma unroll
    for (int ic = 0; ic < 3; ic++)
      s += wc[ic * 3 + 0] * f[ic][h] + wc[ic * 3 + 1] * f[ic][h + 1] + wc[ic * 3 + 2] * f[ic][h + 2];
    orow[(size_t)c * H + h] = (__bf16)fmaxf(s, 0.f);
  }
}

// one wave per row: nll[row] = log(sum_c part_l - PADCOLS) - q[row].ent[tgt]
__global__ void lse_combine(const float* __restrict__ part_l, const float* __restrict__ qf,
                            const float* __restrict__ ent, const int* __restrict__ tt,
                            float* __restrict__ nll)
{
  int gid = blockIdx.x * 256 + threadIdx.x;
  int w = gid >> 6;
  if (w >= NT2) return;
  int lane = gid & 63;
  int j = (w < NT) ? w : w - NT;
  int tgt = (w < NT) ? tt[j * 3 + 2] : tt[j * 3 + 0];
  const float4 qa = ((const float4*)(qf + (size_t)w * H))[lane];
  const float4 ea = ((const float4*)(ent + (size_t)tgt * H))[lane];
  float d = qa.x * ea.x + qa.y * ea.y + qa.z * ea.z + qa.w * ea.w;
  float s = (lane < NCHUNK) ? part_l[(size_t)lane * ROWPAD + w] : 0.f;
  #pragma unroll
  for (int o = 32; o > 0; o >>= 1) {
    d += __shfl_down(d, o, 64);
    s += __shfl_down(s, o, 64);
  }
  if (lane == 0) nll[w] = logf(s - PADCOLS) - d;
}

__global__ void mean_nll(const float* __restrict__ nll, float* __restrict__ out)
{
  float s = 0.f;
  for (int i = threadIdx.x; i < NT2; i += 256) s += nll[i];
  s = block_sum256(s);
  if (threadIdx.x == 0) out[0] = s * (1.f / NT2);
}

// ------------------------- launcher ----------------------------------------
extern "C" void kernel_launch(void* const* d_in, const int* in_sizes, int n_in,
                              void* d_out, int out_size, void* d_ws, size_t ws_size,
                              hipStream_t stream)
{
  const float* dynamic_emb = (const float*)d_in[0];
  const float* emb_rel     = (const float*)d_in[1];
  const float* gru_W_ih    = (const float*)d_in[2];
  const float* gru_W_hh    = (const float*)d_in[3];
  const float* gru_b_ih    = (const float*)d_in[4];
  const float* gru_b_hh    = (const float*)d_in[5];
  const float* agg_W       = (const float*)d_in[6];
  const float* tg_W        = (const float*)d_in[7];
  const float* tg_b        = (const float*)d_in[8];
  const float* hev         = (const float*)d_in[9];
  const float* hrv         = (const float*)d_in[10];
  const float* conv_w      = (const float*)d_in[11];
  const float* conv_b      = (const float*)d_in[12];
  const float* fc_W        = (const float*)d_in[13];
  const float* fc_b        = (const float*)d_in[14];
  const float* sent        = (const float*)d_in[15];
  const int* edge_src = (const int*)d_in[16];
  const int* edge_rel = (const int*)d_in[17];
  const int* edge_dst = (const int*)d_in[18];
  const int* r_to_e   = (const int*)d_in[19];
  const int* r_ids    = (const int*)d_in[20];
  const int* he_row   = (const int*)d_in[21];
  const int* he_col   = (const int*)d_in[22];
  const int* hr_row   = (const int*)d_in[23];
  const int* hr_col   = (const int*)d_in[24];
  const int* tt       = (const int*)d_in[25];
  float* out = (float*)d_out;

  char* base = (char*)d_ws;
  size_t off = 0;
  auto alloc = [&](size_t bytes) { char* p = base + off; off += (bytes + 255) & ~(size_t)255; return p; };

  float* ent    = (float*)alloc((size_t)NE * H * 4);
  float* curr   = (float*)alloc((size_t)NE * H * 4);   // hyper ping-pong; + tgbuf: conv_bf overlay
  float* tgbuf  = (float*)alloc((size_t)NE * H * 4);
  __bf16* convb = (__bf16*)curr;                        // 1600*12800*2 = 40.96 MB spans curr+tgbuf
  __bf16* entb  = (__bf16*)alloc((size_t)NE * H * 2);
  __bf16* entb2 = (__bf16*)alloc((size_t)NE * H * 2);
  __bf16* accEb = (__bf16*)alloc((size_t)NE * H * 2);
  __bf16* ebf   = (__bf16*)alloc((size_t)NEPAD * H * 2);   // frag-packed ent
  __bf16* qbf   = (__bf16*)alloc((size_t)ROWPAD * H * 2);  // frag-packed q
  float* rel    = (float*)alloc((size_t)R2 * H * 4);
  float* accR   = (float*)alloc((size_t)R2 * H * 4);
  __bf16* relb  = (__bf16*)alloc((size_t)R2 * H * 2);
  __bf16* xinb  = (__bf16*)alloc((size_t)R2 * 2 * H * 2);
  float* gi     = (float*)alloc((size_t)R2 * H3 * 4);
  float* gh     = (float*)alloc((size_t)R2 * H3 * 4);
  float* qf     = (float*)alloc((size_t)NT2 * H * 4);
  __bf16* qb    = (__bf16*)alloc((size_t)NT2 * H * 2);
  float* part_l = (float*)alloc((size_t)NCHUNK * ROWPAD * 4);
  float* partM  = (float*)alloc((size_t)R2 * MSPLIT * H * 4);
  float* fcpart = (float*)alloc((size_t)FSPLIT * 1600 * H * 4);   // 32.8 MB
  float* nll    = (float*)alloc((size_t)NT2 * 4);
  __bf16* tgWtb = (__bf16*)alloc((size_t)H * H * 2);
  __bf16* aggWtb= (__bf16*)alloc((size_t)H * H * 2);
  __bf16* fcWtb = (__bf16*)alloc((size_t)H * KFC * 2);
  __bf16* Wihb  = (__bf16*)alloc((size_t)H3 * 2 * H * 2);
  __bf16* Whhb  = (__bf16*)alloc((size_t)H3 * H * 2);

  int* ip = (int*)alloc(0);
  size_t ioff = 0;
  auto ialloc = [&](size_t n) { int* p = ip + ioff; ioff += n; return p; };
  int* fidxM[TT];
  int2* fsrE[TT];
  for (int t = 0; t < TT; t++) fidxM[t] = ialloc(M);
  for (int t = 0; t < TT; t++) fsrE[t] = (int2*)ialloc((size_t)NEDGE * 2);
  int2* fcvHE = (int2*)ialloc((size_t)NNZ_E * 2);
  int2* fcvHR = (int2*)ialloc((size_t)NNZ_R * 2);
  int* cnt_all    = ialloc(CNT_TOTAL);
  int* start_all  = ialloc(CNT_TOTAL);
  int* cursor_all = ialloc(CNT_TOTAL);
  int* bcnt  = ialloc((size_t)4 * NB_CS * 512);
  int* bbase = ialloc((size_t)4 * NB_CS * 512);
  int* bsumNE = ialloc((size_t)4 * NB_NE);

  int* sM[TT];  for (int t = 0; t < TT; t++) sM[t] = start_all + t * 512;
  int* sHR = start_all + 1536;
  int* sE[TT];  for (int t = 0; t < TT; t++) sE[t] = start_all + CNT_NE_BASE + t * CNT_NE_STRIDE;
  int* sHE = start_all + CNT_NE_BASE + 3 * CNT_NE_STRIDE;

  // --- weight prep (bf16) ---
  transpose_cast_k<<<dim3(H / 32, H / 32), 256, 0, stream>>>(tg_W, tgWtb, H, H);
  transpose_cast_k<<<dim3(H / 32, H / 32), 256, 0, stream>>>(agg_W, aggWtb, H, H);
  transpose_cast_k<<<dim3(KFC / 32, H / 32), 256, 0, stream>>>(fc_W, fcWtb, KFC, H);
  cast_bf16_k<<<(H3 * 2 * H / 8 + 255) / 256, 256, 0, stream>>>(gru_W_ih, Wihb, H3 * 2 * H / 8);
  cast_bf16_k<<<(H3 * H / 8 + 255) / 256, 256, 0, stream>>>(gru_W_hh, Whhb, H3 * H / 8);

  // --- CSR build: counting-sort for R2-keyed arrays ---
  cs_hist_k<<<dim3(NB_CS, 4), 256, 0, stream>>>(r_ids, hr_row, bcnt);
  cs_scan_k<<<4, 256, 0, stream>>>(bcnt, bbase, start_all);
  cs_scatter_k<<<dim3(NB_CS, 4), 256, 0, stream>>>(r_ids, r_to_e, hr_row, hr_col, hrv, bbase,
                                                   fidxM[0], fidxM[1], fidxM[2], fcvHR);

  // --- CSR build: NE-keyed arrays (parallel 3-phase scan) ---
  hipMemsetAsync(cnt_all + CNT_NE_BASE, 0, (size_t)(CNT_TOTAL - CNT_NE_BASE) * 4, stream);
  hist_ne_k<<<dim3((NNZ_E + 255) / 256, 4), 256, 0, stream>>>(edge_dst, he_row, cnt_all);
  scan_ne1_k<<<dim3(NB_NE, 4), 256, 0, stream>>>(cnt_all, start_all, bsumNE);
  scan_ne2_k<<<4, 256, 0, stream>>>(bsumNE, start_all);
  scan_ne3_k<<<dim3(NB_NE, 4), 256, 0, stream>>>(start_all, cursor_all, bsumNE);
  perm_fuse2i_k<<<dim3((NEDGE + 255) / 256, 3), 256, 0, stream>>>(
      edge_dst, edge_src, edge_rel, cursor_all, fsrE[0], fsrE[1], fsrE[2]);
  perm_fusevi_k<<<(NNZ_E + 255) / 256, 256, 0, stream>>>(
      he_row, he_col, hev, NNZ_E, cursor_all + CNT_NE_BASE + 3 * CNT_NE_STRIDE, fcvHE);

  constexpr int NEH8 = NE * H / 8, R2H8 = R2 * H / 8;
  constexpr int NE_RB = (NE + 127) / 128;   // 157

  // fused copy + bf16 cast
  copy_cast_k<<<(NEH8 + 255) / 256, 256, 0, stream>>>(dynamic_emb, ent, entb, NEH8);
  copy_cast_k<<<(R2H8 + 255) / 256, 256, 0, stream>>>(emb_rel, rel, relb, R2H8);

  for (int t = 0; t < TT; t++) {
    // --- rel update (GRU) ---
    gather_mean2_k<<<dim3(R2, MSPLIT), 256, 0, stream>>>(entb, fidxM[t], sM[t], partM);
    mean_xin_k<<<R2, 256, 0, stream>>>(partM, sM[t], rel, xinb);
    gru_gemm2_k<<<dim3(H3 / 64, (R2 + 63) / 64, 2), 256, 0, stream>>>(
        xinb, relb, Wihb, Whhb, gru_b_ih, gru_b_hh, gi, gh);
    gru_combine<<<(R2 * H + 255) / 256, 256, 0, stream>>>(gi, gh, rel, relb);

    // --- ent update: gate, gather, agg+blend (fused) ---
    panel2_gemm<2><<<dim3(2, NE_RB), 256, 0, stream>>>(
        entb, tgWtb, tg_b, tgbuf, NE, H, 2, nullptr, nullptr, nullptr);
    gather_edges3_k<<<NE, 256, 0, stream>>>(entb, relb, fsrE[t], sE[t], accEb);
    panel2_gemm<4><<<dim3(2, NE_RB), 256, 0, stream>>>(
        accEb, aggWtb, nullptr, nullptr, NE, H, 2, tgbuf, ent, entb);
  }

  // --- hypergraph layers ---
  hyper3_k<<<NE, 256, 0, stream>>>(ent, entb, fcvHE, sHE, curr, entb2);
  hyper3_k<<<NE, 256, 0, stream>>>(curr, entb2, fcvHE, sHE, ent, entb);
  hyper_rel_k<<<R2, 256, 0, stream>>>(rel, fcvHR, sHR, accR);
  hyper_rel_k<<<R2, 256, 0, stream>>>(accR, fcvHR, sHR, rel);

  // frag-pack final ent for scores B
  pack_frag_k<<<(NEPAD * 32 + 255) / 256, 256, 0, stream>>>(entb, ebf, NEPAD * 32, NE);

  // --- conv + fc (3 chunks: 1600, 1600, 800 rows) ---
  for (int c = 0; c < 3; c++) {
    int row0 = c * 1600;
    int rows = min(1600, NT2 - row0);
    conv_feat<<<rows, 256, 0, stream>>>(ent, rel, sent, tt, conv_w, conv_b, convb, row0);
    fc_gemm<<<dim3(FSPLIT, (rows + 127) / 128), 256, 0, stream>>>(convb, fcWtb, fcpart, rows);
    fc_reduce<<<(rows * H + 255) / 256, 256, 0, stream>>>(
        fcpart, fc_b, qf + (size_t)row0 * H, qb + (size_t)row0 * H, rows);
  }

  // frag-pack q for scores A
  pack_frag_k<<<(ROWPAD * 32 + 255) / 256, 256, 0, stream>>>(qb, qbf, ROWPAD * 32, NT2);

  // --- fused scores + LSE ---
  scores_v3<<<dim3(NCHUNK, 16), 256, 0, stream>>>(qbf, ebf, part_l);
  lse_combine<<<(NT2 * 64 + 255) / 256, 256, 0, stream>>>(part_l, qf, ent, tt, nll);
  mean_nll<<<1, 256, 0, stream>>>(nll, out);
}

// Round 13
// 801.248 us; speedup vs baseline: 1.1963x; 1.1963x over previous
//
#include <hip/hip_runtime.h>
#include <math.h>

#define DEV_INLINE __device__ __forceinline__

constexpr int H      = 256;
constexpr int NE     = 20000;
constexpr int NR     = 250;
constexpr int R2     = 500;
constexpr int TT     = 3;
constexpr int NEDGE  = 150000;
constexpr int M      = 200000;
constexpr int NNZ_E  = 320000;
constexpr int NNZ_R  = 8000;
constexpr int CH     = 50;
constexpr int NT     = 2000;
constexpr int NT2    = 4000;
constexpr int H3     = 3 * H;     // 768
constexpr int KFC    = CH * H;    // 12800
constexpr int ROWPAD = 4096;
constexpr int NCHUNK = 32;        // scores col chunks
constexpr int SPP    = 20;        // 32-col panels per chunk (scores_v4)
constexpr int MSPLIT = 8;         // gather_mean row split
constexpr int FSPLIT = 20;        // fc split-K
constexpr int NB_CS  = 64;        // counting-sort blocks per R2 array
constexpr int NEPAD  = 20480;     // ent rows padded to 64
constexpr int NB_NE  = 80;        // NE-scan blocks per array
constexpr float PADCOLS = 480.f;  // NEPAD - NE: exp2(0) contributions to subtract

// cnt/start/cursor packed region (ints)
constexpr int CNT_NE_BASE   = 2048;
constexpr int CNT_NE_STRIDE = 20224;
constexpr int CNT_TOTAL     = CNT_NE_BASE + 4 * CNT_NE_STRIDE;  // 82944

typedef __bf16 bf16x8 __attribute__((ext_vector_type(8)));
typedef float  f32x4  __attribute__((ext_vector_type(4)));

DEV_INLINE bf16x8 ldb8(const __bf16* p) { return *(const bf16x8*)p; }
DEV_INLINE bf16x8 zerob8() { uint4 z = make_uint4(0, 0, 0, 0); return __builtin_bit_cast(bf16x8, z); }
DEV_INLINE f32x4 mfma16(bf16x8 a, bf16x8 b, f32x4 c) {
  return __builtin_amdgcn_mfma_f32_16x16x32_bf16(a, b, c, 0, 0, 0);
}
DEV_INLINE void gload_lds16(const void* g, void* l) {
  __builtin_amdgcn_global_load_lds((const __attribute__((address_space(1))) void*)g,
                                   (__attribute__((address_space(3))) void*)l, 16, 0, 0);
}

// ------------------------- block reduction (blockDim == 256) ---------------
DEV_INLINE float block_sum256(float v) {
  __shared__ float ws[4];
  #pragma unroll
  for (int o = 32; o > 0; o >>= 1) v += __shfl_down(v, o, 64);
  if ((threadIdx.x & 63) == 0) ws[threadIdx.x >> 6] = v;
  __syncthreads();
  float r = ws[0] + ws[1] + ws[2] + ws[3];
  __syncthreads();
  return r;
}

// ------------------- counting-sort CSR (R2-keyed arrays) -------------------
__global__ void cs_hist_k(const int* __restrict__ r_ids, const int* __restrict__ hr_row,
                          int* __restrict__ bcnt)
{
  __shared__ int lh[512];
  int a = blockIdx.y;
  const int* keys = (a < 3) ? r_ids + (size_t)a * M : hr_row;
  int n = (a < 3) ? M : NNZ_R;
  int t = threadIdx.x;
  lh[t] = 0; lh[t + 256] = 0;
  __syncthreads();
  int chunk = (n + NB_CS - 1) / NB_CS;
  int i0 = blockIdx.x * chunk, i1 = min(i0 + chunk, n);
  for (int i = i0 + t; i < i1; i += 256) atomicAdd(&lh[keys[i]], 1);
  __syncthreads();
  int* outp = bcnt + ((size_t)a * NB_CS + blockIdx.x) * 512;
  outp[t] = lh[t]; outp[t + 256] = lh[t + 256];
}

__global__ void cs_scan_k(const int* __restrict__ bcnt, int* __restrict__ bbase,
                          int* __restrict__ start_all)
{
  __shared__ int ps[257];
  int a = blockIdx.x;
  int* start = start_all + ((a < 3) ? a * 512 : 1536);
  const int* bc = bcnt + (size_t)a * NB_CS * 512;
  int* bb = bbase + (size_t)a * NB_CS * 512;
  int t = threadIdx.x;
  int b0 = 2 * t, b1 = 2 * t + 1;
  int tot0 = 0, tot1 = 0;
  for (int blk = 0; blk < NB_CS; blk++) {
    tot0 += bc[blk * 512 + b0];
    tot1 += bc[blk * 512 + b1];
  }
  ps[t + 1] = tot0 + tot1;
  if (t == 0) ps[0] = 0;
  __syncthreads();
  if (t == 0) { for (int i = 1; i <= 256; i++) ps[i] += ps[i - 1]; }
  __syncthreads();
  int run0 = ps[t], run1 = ps[t] + tot0;
  start[b0] = run0;
  start[b1] = run1;
  for (int blk = 0; blk < NB_CS; blk++) {
    bb[blk * 512 + b0] = run0; run0 += bc[blk * 512 + b0];
    bb[blk * 512 + b1] = run1; run1 += bc[blk * 512 + b1];
  }
}

__global__ void cs_scatter_k(const int* __restrict__ r_ids, const int* __restrict__ r_to_e,
                             const int* __restrict__ hr_row, const int* __restrict__ hr_col,
                             const float* __restrict__ hrv, const int* __restrict__ bbase,
                             int* __restrict__ f0, int* __restrict__ f1, int* __restrict__ f2,
                             int2* __restrict__ fcvHR)
{
  __shared__ int cur[512];
  int a = blockIdx.y;
  const int* keys = (a < 3) ? r_ids + (size_t)a * M : hr_row;
  int n = (a < 3) ? M : NNZ_R;
  int t = threadIdx.x;
  const int* bb = bbase + ((size_t)a * NB_CS + blockIdx.x) * 512;
  cur[t] = bb[t]; cur[t + 256] = bb[t + 256];
  __syncthreads();
  int chunk = (n + NB_CS - 1) / NB_CS;
  int i0 = blockIdx.x * chunk, i1 = min(i0 + chunk, n);
  if (a < 3) {
    const int* other = r_to_e + (size_t)a * M;
    int* f = (a == 0) ? f0 : (a == 1) ? f1 : f2;
    for (int i = i0 + t; i < i1; i += 256) {
      int p = atomicAdd(&cur[keys[i]], 1);
      f[p] = other[i];
    }
  } else {
    for (int i = i0 + t; i < i1; i += 256) {
      int p = atomicAdd(&cur[keys[i]], 1);
      fcvHR[p] = make_int2(hr_col[i], __float_as_int(hrv[i]));
    }
  }
}

// ------------------- NE-keyed CSR (low contention) -------------------------
__global__ void hist_ne_k(const int* __restrict__ edge_dst, const int* __restrict__ he_row,
                          int* __restrict__ cnt_all)
{
  int a = blockIdx.y;
  const int* keys = (a < 3) ? edge_dst + (size_t)a * NEDGE : he_row;
  int n = (a < 3) ? NEDGE : NNZ_E;
  int* cnt = cnt_all + CNT_NE_BASE + a * CNT_NE_STRIDE;
  int i = blockIdx.x * 256 + threadIdx.x;
  if (i < n) atomicAdd(&cnt[keys[i]], 1);
}

__global__ void scan_ne1_k(const int* __restrict__ cnt_all, int* __restrict__ start_all,
                           int* __restrict__ bsum)
{
  __shared__ int wtot[4];
  int a = blockIdx.y;
  int off = CNT_NE_BASE + a * CNT_NE_STRIDE;
  int bin = blockIdx.x * 256 + threadIdx.x;
  int lane = threadIdx.x & 63, w = threadIdx.x >> 6;
  int v = (bin < NE) ? cnt_all[off + bin] : 0;
  int orig = v;
  #pragma unroll
  for (int o = 1; o < 64; o <<= 1) {
    int n = __shfl_up(v, o, 64);
    if (lane >= o) v += n;
  }
  if (lane == 63) wtot[w] = v;
  __syncthreads();
  int wo = 0;
  #pragma unroll
  for (int i = 0; i < 4; i++) if (i < w) wo += wtot[i];
  if (bin < NE) start_all[off + bin] = v - orig + wo;
  if (threadIdx.x == 255) bsum[a * NB_NE + blockIdx.x] = wo + v;
}

__global__ void scan_ne2_k(int* __restrict__ bsum, int* __restrict__ start_all)
{
  __shared__ int s[NB_NE + 1];
  int a = blockIdx.x;
  int t = threadIdx.x;
  if (t < NB_NE) s[t + 1] = bsum[a * NB_NE + t];
  if (t == 0) s[0] = 0;
  __syncthreads();
  if (t == 0) { for (int i = 1; i <= NB_NE; i++) s[i] += s[i - 1]; }
  __syncthreads();
  if (t < NB_NE) bsum[a * NB_NE + t] = s[t];
  if (t == 0) start_all[CNT_NE_BASE + a * CNT_NE_STRIDE + NE] = s[NB_NE];
}

__global__ void scan_ne3_k(int* __restrict__ start_all, int* __restrict__ cursor_all,
                           const int* __restrict__ bsum)
{
  int a = blockIdx.y;
  int off = CNT_NE_BASE + a * CNT_NE_STRIDE;
  int bin = blockIdx.x * 256 + threadIdx.x;
  if (bin >= NE) return;
  int v = start_all[off + bin] + bsum[a * NB_NE + blockIdx.x];
  start_all[off + bin] = v;
  cursor_all[off + bin] = v;
}

// batched: 3 edge arrays in one launch (grid.y = 3)
__global__ void perm_fuse2i_k(const int* __restrict__ edge_dst, const int* __restrict__ edge_src,
                              const int* __restrict__ edge_rel, int* __restrict__ cursor_all,
                              int2* __restrict__ f0, int2* __restrict__ f1, int2* __restrict__ f2)
{
  int a = blockIdx.y;
  const int* keys = edge_dst + (size_t)a * NEDGE;
  const int* o1 = edge_src + (size_t)a * NEDGE;
  const int* o2 = edge_rel + (size_t)a * NEDGE;
  int* cursor = cursor_all + CNT_NE_BASE + a * CNT_NE_STRIDE;
  int2* f = (a == 0) ? f0 : (a == 1) ? f1 : f2;
  int i = blockIdx.x * 256 + threadIdx.x;
  if (i < NEDGE) { int p = atomicAdd(&cursor[keys[i]], 1); f[p] = make_int2(o1[i], o2[i]); }
}
__global__ void perm_fusevi_k(const int* __restrict__ keys, const int* __restrict__ col,
                              const float* __restrict__ val, int n, int* __restrict__ cursor,
                              int2* __restrict__ f)
{
  int i = blockIdx.x * 256 + threadIdx.x;
  if (i < n) {
    int p = atomicAdd(&cursor[keys[i]], 1);
    f[p] = make_int2(col[i], __float_as_int(val[i]));
  }
}

// ------------------------- casts / transposes ------------------------------
__global__ void cast_bf16_k(const float* __restrict__ in, __bf16* __restrict__ out, int n8)
{
  int i = blockIdx.x * 256 + threadIdx.x;
  if (i >= n8) return;
  const float4* p = (const float4*)in + (size_t)i * 2;
  float4 u = p[0], v = p[1];
  bf16x8 o;
  o[0] = (__bf16)u.x; o[1] = (__bf16)u.y; o[2] = (__bf16)u.z; o[3] = (__bf16)u.w;
  o[4] = (__bf16)v.x; o[5] = (__bf16)v.y; o[6] = (__bf16)v.z; o[7] = (__bf16)v.w;
  ((bf16x8*)out)[i] = o;
}

// copy fp32 + emit bf16 in one pass
__global__ void copy_cast_k(const float* __restrict__ in, float* __restrict__ outf,
                            __bf16* __restrict__ outb, int n8)
{
  int i = blockIdx.x * 256 + threadIdx.x;
  if (i >= n8) return;
  const float4* p = (const float4*)in + (size_t)i * 2;
  float4 u = p[0], v = p[1];
  ((float4*)outf)[(size_t)i * 2]     = u;
  ((float4*)outf)[(size_t)i * 2 + 1] = v;
  bf16x8 o;
  o[0] = (__bf16)u.x; o[1] = (__bf16)u.y; o[2] = (__bf16)u.z; o[3] = (__bf16)u.w;
  o[4] = (__bf16)v.x; o[5] = (__bf16)v.y; o[6] = (__bf16)v.z; o[7] = (__bf16)v.w;
  ((bf16x8*)outb)[i] = o;
}

__global__ void transpose_cast_k(const float* __restrict__ in, __bf16* __restrict__ out,
                                 int K, int N)
{
  __shared__ float tile[32][33];
  int tx = threadIdx.x & 31, ty = threadIdx.x >> 5;   // 32 x 8
  int kb = blockIdx.x * 32, nb = blockIdx.y * 32;
  #pragma unroll
  for (int i = 0; i < 4; i++)
    tile[ty + i * 8][tx] = in[(size_t)(kb + ty + i * 8) * N + nb + tx];
  __syncthreads();
  #pragma unroll
  for (int i = 0; i < 4; i++)
    out[(size_t)(nb + ty + i * 8) * K + kb + tx] = (__bf16)tile[tx][ty + i * 8];
}

// reorder [rows][256] bf16 into MFMA-frag-linear layout
__global__ void pack_frag_k(const __bf16* __restrict__ src, __bf16* __restrict__ dst,
                            int nchunks, int Mr)
{
  int i = blockIdx.x * 256 + threadIdx.x;
  if (i >= nchunks) return;
  int c = i >> 5, s = i & 31;
  bf16x8 v = (c < Mr) ? ldb8(src + (size_t)c * H + s * 8) : zerob8();
  int kf = s >> 2, kg = s & 3;
  size_t d = ((((size_t)(c >> 6) * 4 + ((c >> 4) & 3)) * 8 + kf) * 4 + kg) * 16 + (c & 15);
  *(bf16x8*)(dst + d * 8) = v;
}

// ------------------------- gather kernels (16 B/lane, 32-lane halves) ------
__global__ void gather_mean2_k(const __bf16* __restrict__ src, const int* __restrict__ fidx,
                               const int* __restrict__ start, float* __restrict__ part)
{
  __shared__ __align__(16) float red[4][H];
  int r = blockIdx.x, s = blockIdx.y;
  int s0 = start[r], s1 = start[r + 1];
  int len = s1 - s0;
  int chunk = (len + MSPLIT - 1) / MSPLIT;
  int jb = s0 + s * chunk, je = min(jb + chunk, s1);
  int tid = threadIdx.x, lane = tid & 63, w = tid >> 6;
  int half = lane >> 5, l = lane & 31;
  float acc[8] = {0.f, 0.f, 0.f, 0.f, 0.f, 0.f, 0.f, 0.f};
  for (int j = jb + w * 2 + half; j < je; j += 8) {
    int e = fidx[j];
    bf16x8 v = ldb8(src + (size_t)e * H + l * 8);
    #pragma unroll
    for (int q = 0; q < 8; q++) acc[q] += (float)v[q];
  }
  #pragma unroll
  for (int q = 0; q < 8; q++) acc[q] += __shfl_xor(acc[q], 32, 64);
  if (half == 0) {
    *(float4*)&red[w][l * 8]     = make_float4(acc[0], acc[1], acc[2], acc[3]);
    *(float4*)&red[w][l * 8 + 4] = make_float4(acc[4], acc[5], acc[6], acc[7]);
  }
  __syncthreads();
  int h = tid;
  part[((size_t)r * MSPLIT + s) * H + h] = red[0][h] + red[1][h] + red[2][h] + red[3][h];
}

__global__ void mean_xin_k(const float* __restrict__ partM, const int* __restrict__ start,
                           const float* __restrict__ rel, __bf16* __restrict__ xin)
{
  int r = blockIdx.x, h = threadIdx.x;
  float s = 0.f;
  #pragma unroll
  for (int z = 0; z < MSPLIT; z++) s += partM[((size_t)r * MSPLIT + z) * H + h];
  float xm = s / (float)max(start[r + 1] - start[r], 1);
  xin[(size_t)r * 2 * H + h]     = (__bf16)rel[(size_t)r * H + h];
  xin[(size_t)r * 2 * H + H + h] = (__bf16)xm;
}

__global__ void gather_edges3_k(const __bf16* __restrict__ ent, const __bf16* __restrict__ rel,
                                const int2* __restrict__ fsr,
                                const int* __restrict__ start, __bf16* __restrict__ out)
{
  __shared__ __align__(16) float red[4][H];
  int d = blockIdx.x;
  int s0 = start[d], s1 = start[d + 1];
  int tid = threadIdx.x, lane = tid & 63, w = tid >> 6;
  int half = lane >> 5, l = lane & 31;
  const __bf16* srcbase = half ? rel : ent;
  float acc[8] = {0.f, 0.f, 0.f, 0.f, 0.f, 0.f, 0.f, 0.f};
  for (int j = s0 + w; j < s1; j += 4) {
    int2 e2 = fsr[j];
    int e = half ? e2.y : e2.x;
    bf16x8 v = ldb8(srcbase + (size_t)e * H + l * 8);
    #pragma unroll
    for (int q = 0; q < 8; q++) acc[q] += (float)v[q];
  }
  #pragma unroll
  for (int q = 0; q < 8; q++) acc[q] += __shfl_xor(acc[q], 32, 64);
  if (half == 0) {
    *(float4*)&red[w][l * 8]     = make_float4(acc[0], acc[1], acc[2], acc[3]);
    *(float4*)&red[w][l * 8 + 4] = make_float4(acc[4], acc[5], acc[6], acc[7]);
  }
  __syncthreads();
  int h = tid;
  float sum = red[0][h] + red[1][h] + red[2][h] + red[3][h];
  out[(size_t)d * H + h] = (__bf16)(sum / (float)max(s1 - s0, 1));
}

__global__ void hyper3_k(const float* __restrict__ x, const __bf16* __restrict__ xb,
                         const int2* __restrict__ fcv,
                         const int* __restrict__ start,
                         float* __restrict__ xout, __bf16* __restrict__ xoutb)
{
  __shared__ __align__(16) float red[4][H];
  int r = blockIdx.x;
  int s0 = start[r], s1 = start[r + 1];
  int tid = threadIdx.x, lane = tid & 63, w = tid >> 6;
  int half = lane >> 5, l = lane & 31;
  float acc[8] = {0.f, 0.f, 0.f, 0.f, 0.f, 0.f, 0.f, 0.f};
  for (int j = s0 + w * 2 + half; j < s1; j += 8) {
    int2 cv = fcv[j];
    float wt = __int_as_float(cv.y);
    bf16x8 v = ldb8(xb + (size_t)cv.x * H + l * 8);
    #pragma unroll
    for (int q = 0; q < 8; q++) acc[q] += wt * (float)v[q];
  }
  #pragma unroll
  for (int q = 0; q < 8; q++) acc[q] += __shfl_xor(acc[q], 32, 64);
  if (half == 0) {
    *(float4*)&red[w][l * 8]     = make_float4(acc[0], acc[1], acc[2], acc[3]);
    *(float4*)&red[w][l * 8 + 4] = make_float4(acc[4], acc[5], acc[6], acc[7]);
  }
  __syncthreads();
  int h = tid;
  float y = red[0][h] + red[1][h] + red[2][h] + red[3][h];
  float ss = block_sum256(y * y);
  float rn = 1.f / fmaxf(sqrtf(ss), 1e-12f);
  float o = x[(size_t)r * H + h] + y * rn;
  xout[(size_t)r * H + h] = o;
  xoutb[(size_t)r * H + h] = (__bf16)o;
}

__global__ void hyper_rel_k(const float* __restrict__ x, const int2* __restrict__ fcv,
                            const int* __restrict__ start, float* __restrict__ xout)
{
  int r = blockIdx.x, h = threadIdx.x;
  int s0 = start[r], s1 = start[r + 1];
  float a0 = 0.f;
  for (int j = s0; j < s1; j++) {
    int2 cv = fcv[j];
    a0 += __int_as_float(cv.y) * x[(size_t)cv.x * H + h];
  }
  float ss = block_sum256(a0 * a0);
  float rn = 1.f / fmaxf(sqrtf(ss), 1e-12f);
  xout[(size_t)r * H + h] = x[(size_t)r * H + h] + a0 * rn;
}

// ------------------------- small elementwise -------------------------------
__global__ void gru_combine(const float* __restrict__ gi, const float* __restrict__ gh,
                            float* __restrict__ rel, __bf16* __restrict__ relb)
{
  int idx = blockIdx.x * 256 + threadIdx.x;       // R2 * H
  if (idx >= R2 * H) return;
  int i = idx >> 8, h = idx & 255;
  const float* gir = gi + (size_t)i * H3;
  const float* ghr = gh + (size_t)i * H3;
  float r = 1.f / (1.f + __expf(-(gir[h]       + ghr[h])));
  float z = 1.f / (1.f + __expf(-(gir[H + h]   + ghr[H + h])));
  float n = tanhf(gir[2 * H + h] + r * ghr[2 * H + h]);
  float o = (1.f - z) * n + z * rel[idx];
  rel[idx] = o;
  relb[idx] = (__bf16)o;
}

// ------------------------- panel2 GEMM (K=256, 64-col B panels) -------------
DEV_INLINE void stage64_load(uint4* v, const __bf16* src, int rowBase, int rowLimit, int tid)
{
  #pragma unroll
  for (int q = 0; q < 8; q++) {
    int X = (q * 256 + tid) * 16;
    int row = X >> 9, boff = X & 511;
    int grow = min(rowBase + row, rowLimit);
    v[q] = *(const uint4*)((const char*)src + (size_t)grow * 512 + boff);
  }
}
DEV_INLINE void stage64_write(char* lds, const uint4* v, int tid)
{
  #pragma unroll
  for (int q = 0; q < 8; q++) {
    int X = (q * 256 + tid) * 16;
    int row = X >> 9;
    *(uint4*)(lds + (X ^ ((row & 7) << 4))) = v[q];
  }
}
DEV_INLINE bf16x8 frag64(const char* lds, int row, int kf, int kg)
{
  int off = (kf * 64 + kg * 16) ^ ((row & 7) << 4);
  return *(const bf16x8*)(lds + row * 512 + off);
}

// EPI: 2 = bias+sigmoid store to out; 4 = relu + gate-blend, writes entf/entbo
// PS = 1: each block handles one 64-col panel (grid.x = N/64)
template<int EPI>
__global__ __launch_bounds__(256, 2) void panel2_gemm(const __bf16* __restrict__ A,
                                                      const __bf16* __restrict__ B,
                                                      const float* __restrict__ bias,
                                                      float* __restrict__ out,
                                                      int Mr, int N,
                                                      const float* __restrict__ gate,
                                                      float* __restrict__ entf,
                                                      __bf16* __restrict__ entbo)
{
  __shared__ __attribute__((aligned(16))) char lds0[32768];
  __shared__ __attribute__((aligned(16))) char lds1[32768];
  int tid = threadIdx.x;
  int lane = tid & 63, wM = tid >> 6;
  int r = lane & 15, kg = lane >> 4;
  int rowBase = blockIdx.y * 128;

  {
    uint4 va[8];
    stage64_load(va, A, rowBase, Mr - 1, tid);
    stage64_write(lds0, va, tid);
    stage64_load(va, A, rowBase + 64, Mr - 1, tid);
    stage64_write(lds1, va, tid);
  }
  __syncthreads();

  bf16x8 a[2][8];
  {
    int base = wM * 32;
    const char* ab = (base >= 64) ? lds1 : lds0;
    #pragma unroll
    for (int i = 0; i < 2; i++) {
      int ar = (base + i * 16 + r) & 63;
      #pragma unroll
      for (int kf = 0; kf < 8; kf++) a[i][kf] = frag64(ab, ar, kf, kg);
    }
  }
  __syncthreads();
  {
    uint4 va[8];
    stage64_load(va, B, blockIdx.x * 64, N - 1, tid);
    stage64_write(lds0, va, tid);
  }
  __syncthreads();

  f32x4 acc[2][4];
  #pragma unroll
  for (int i = 0; i < 2; i++)
    #pragma unroll
    for (int j = 0; j < 4; j++) {
      acc[i][j][0] = 0.f; acc[i][j][1] = 0.f; acc[i][j][2] = 0.f; acc[i][j][3] = 0.f;
    }
  __builtin_amdgcn_s_setprio(1);
  #pragma unroll
  for (int kf = 0; kf < 8; kf++) {
    bf16x8 b[4];
    #pragma unroll
    for (int j = 0; j < 4; j++) b[j] = frag64(lds0, j * 16 + r, kf, kg);
    #pragma unroll
    for (int i = 0; i < 2; i++)
      #pragma unroll
      for (int j = 0; j < 4; j++)
        acc[i][j] = mfma16(a[i][kf], b[j], acc[i][j]);
  }
  __builtin_amdgcn_s_setprio(0);

  #pragma unroll
  for (int i = 0; i < 2; i++)
    #pragma unroll
    for (int g = 0; g < 4; g++) {
      int row = rowBase + wM * 32 + i * 16 + kg * 4 + g;
      if (row >= Mr) continue;
      #pragma unroll
      for (int j = 0; j < 4; j++) {
        int col = blockIdx.x * 64 + j * 16 + r;
        if (col >= N) continue;
        float v = acc[i][j][g];
        if (EPI == 2) {
          if (bias) v += bias[col];
          v = 1.f / (1.f + __expf(-v));
          out[(size_t)row * N + col] = v;
        } else {   // EPI == 4: relu + gate blend + dual store
          v = fmaxf(v, 0.f);
          size_t idx = (size_t)row * N + col;
          float t = gate[idx];
          float o = t * v + (1.f - t) * entf[idx];
          entf[idx] = o;
          entbo[idx] = (__bf16)o;
        }
      }
    }
}

// ------------------------- scores_v4 (frag-packed, 32-col panels) ----------
// A: qbf frag-packed (4096 rows). B: ebf frag-packed (20480 cols).
// Block = 4 waves x 32 rows = 128 rows; grid (NCHUNK=32, 32).
// 32-col panels (16 KB) double-buffered in 32 KB LDS -> 3 blocks/CU.
__global__ __launch_bounds__(256, 3) void scores_v4(const __bf16* __restrict__ qbf,
                                                    const __bf16* __restrict__ ebf,
                                                    float* __restrict__ part_l)
{
  __shared__ __attribute__((aligned(16))) char lds[2][16384];
  int tid = threadIdx.x, lane = tid & 63, w = tid >> 6;
  int r = lane & 15, kg = lane >> 4;

  auto stage = [&](int buf, int p) {
    const char* g = (const char*)ebf + ((size_t)(blockIdx.x * SPP + p)) * 16384;
    int wbase = (tid & ~63) * 16;
    #pragma unroll
    for (int q = 0; q < 4; q++) {
      int o = q * 4096 + wbase;
      gload_lds16(g + o + lane * 16, lds[buf] + o);
    }
  };

  stage(0, 0);

  // A fragments: block rows = by*128 + w*32; chunk cb = by*2 + (w>>1),
  // sub-tile j' = (w&1)*2 + i
  bf16x8 a[2][8];
  {
    int cb = blockIdx.y * 2 + (w >> 1);
    int jb = (w & 1) * 2;
    const __bf16* ap = qbf + (size_t)cb * 16384 + kg * 128 + r * 8;
    #pragma unroll
    for (int i = 0; i < 2; i++)
      #pragma unroll
      for (int kf = 0; kf < 8; kf++)
        a[i][kf] = ldb8(ap + ((jb + i) * 8 + kf) * 512);
  }
  __syncthreads();   // panel 0 landed

  float lsum[2][4];
  #pragma unroll
  for (int i = 0; i < 2; i++)
    #pragma unroll
    for (int g = 0; g < 4; g++) lsum[i][g] = 0.f;

  const char* l0 = lds[0] + kg * 256 + r * 16;
  const char* l1 = lds[1] + kg * 256 + r * 16;

  for (int p = 0; p < SPP; p++) {
    if (p + 1 < SPP) stage((p + 1) & 1, p + 1);   // loads in flight across MFMA
    const char* cur = (p & 1) ? l1 : l0;

    f32x4 acc[2][2];
    #pragma unroll
    for (int i = 0; i < 2; i++)
      #pragma unroll
      for (int j = 0; j < 2; j++) {
        acc[i][j][0] = 0.f; acc[i][j][1] = 0.f; acc[i][j][2] = 0.f; acc[i][j][3] = 0.f;
      }
    __builtin_amdgcn_s_setprio(1);
    #pragma unroll
    for (int kf = 0; kf < 8; kf++) {
      bf16x8 b0 = *(const bf16x8*)(cur + (0 * 8 + kf) * 1024);
      bf16x8 b1 = *(const bf16x8*)(cur + (1 * 8 + kf) * 1024);
      acc[0][0] = mfma16(a[0][kf], b0, acc[0][0]);
      acc[0][1] = mfma16(a[0][kf], b1, acc[0][1]);
      acc[1][0] = mfma16(a[1][kf], b0, acc[1][0]);
      acc[1][1] = mfma16(a[1][kf], b1, acc[1][1]);
    }
    __builtin_amdgcn_s_setprio(0);

    // padded cols contribute exp2(0)=1 each; corrected in lse_combine
    #pragma unroll
    for (int j = 0; j < 2; j++)
      #pragma unroll
      for (int i = 0; i < 2; i++)
        #pragma unroll
        for (int g = 0; g < 4; g++)
          lsum[i][g] += exp2f(acc[i][j][g]);
    __syncthreads();   // drains next-panel loads + all waves done with cur
  }

  #pragma unroll
  for (int m = 1; m < 16; m <<= 1)
    #pragma unroll
    for (int i = 0; i < 2; i++)
      #pragma unroll
      for (int g = 0; g < 4; g++)
        lsum[i][g] += __shfl_xor(lsum[i][g], m, 64);
  if (r == 0) {
    #pragma unroll
    for (int i = 0; i < 2; i++)
      #pragma unroll
      for (int g = 0; g < 4; g++) {
        int row = blockIdx.y * 128 + w * 32 + i * 16 + kg * 4 + g;
        part_l[(size_t)blockIdx.x * ROWPAD + row] = lsum[i][g];
      }
  }
}

// ------------------------- fc GEMM (K = 12800, LDS-staged, split-K=20) -----
__global__ __launch_bounds__(256) void fc_gemm(const __bf16* __restrict__ A,
                                               const __bf16* __restrict__ Bt,
                                               float* __restrict__ part, int Mr)
{
  __shared__ __attribute__((aligned(16))) char lds[49152];
  int tid = threadIdx.x;
  int lane = tid & 63, wave = tid >> 6;
  int wM = wave >> 1, wN = wave & 1;
  int r = lane & 15, kg = lane >> 4;
  int rowBase = blockIdx.y * 128;
  int kbeg = blockIdx.x * (KFC / FSPLIT);   // 640

  f32x4 acc[4][8];
  #pragma unroll
  for (int i = 0; i < 4; i++)
    #pragma unroll
    for (int j = 0; j < 8; j++) {
      acc[i][j][0] = 0.f; acc[i][j][1] = 0.f; acc[i][j][2] = 0.f; acc[i][j][3] = 0.f;
    }

  for (int ks = 0; ks < KFC / FSPLIT / 64; ks++) {
    int kb = kbeg + ks * 64;
    #pragma unroll
    for (int q = 0; q < 12; q++) {
      int X = (q * 256 + tid) * 16;
      int row = X >> 7;
      int off = X & 127;
      int soff = off ^ ((row & 7) << 4);
      uint4 v;
      if (row < 128) {
        int grow = min(rowBase + row, Mr - 1);
        v = *(const uint4*)((const char*)A + (size_t)grow * (KFC * 2) + kb * 2 + soff);
      } else {
        int col = row - 128;
        v = *(const uint4*)((const char*)Bt + (size_t)col * (KFC * 2) + kb * 2 + soff);
      }
      *(uint4*)(lds + X) = v;
    }
    __syncthreads();
    #pragma unroll
    for (int kf = 0; kf < 2; kf++) {
      bf16x8 a[4], b[8];
      #pragma unroll
      for (int i = 0; i < 4; i++) {
        int row = wM * 64 + i * 16 + r;
        int off = (kf * 64 + kg * 16) ^ ((row & 7) << 4);
        a[i] = *(const bf16x8*)(lds + row * 128 + off);
      }
      #pragma unroll
      for (int j = 0; j < 8; j++) {
        int row = 128 + wN * 128 + j * 16 + r;
        int off = (kf * 64 + kg * 16) ^ ((row & 7) << 4);
        b[j] = *(const bf16x8*)(lds + row * 128 + off);
      }
      #pragma unroll
      for (int i = 0; i < 4; i++)
        #pragma unroll
        for (int j = 0; j < 8; j++)
          acc[i][j] = mfma16(a[i], b[j], acc[i][j]);
    }
    __syncthreads();
  }

  float* pz = part + (size_t)blockIdx.x * Mr * H;
  #pragma unroll
  for (int i = 0; i < 4; i++)
    #pragma unroll
    for (int g = 0; g < 4; g++) {
      int row = rowBase + wM * 64 + i * 16 + kg * 4 + g;
      if (row >= Mr) continue;
      #pragma unroll
      for (int j = 0; j < 8; j++) {
        int col = wN * 128 + j * 16 + r;
        pz[(size_t)row * H + col] = acc[i][j][g];
      }
    }
}

// ------------------------- GRU dual GEMM (z=0: gi, z=1: gh) ----------------
__global__ void gru_gemm2_k(const __bf16* __restrict__ xinb, const __bf16* __restrict__ relb,
                            const __bf16* __restrict__ Wihb, const __bf16* __restrict__ Whhb,
                            const float* __restrict__ b_ih, const float* __restrict__ b_hh,
                            float* __restrict__ gi, float* __restrict__ gh)
{
  const __bf16* A; const __bf16* Bt; const float* bias; float* C; int K;
  if (blockIdx.z == 0) { A = xinb; Bt = Wihb; bias = b_ih; C = gi; K = 2 * H; }
  else                 { A = relb; Bt = Whhb; bias = b_hh; C = gh; K = H; }
  const int Mr = R2, N = H3;

  int lane = threadIdx.x & 63, wave = threadIdx.x >> 6;
  int waveM = wave >> 1, waveN = wave & 1;
  int r = lane & 15, kg = lane >> 4;
  int rowBase = blockIdx.y * 64 + waveM * 32;
  int colBase = blockIdx.x * 64 + waveN * 32;

  int row0 = rowBase + r, row1 = rowBase + 16 + r;
  int col0 = colBase + r, col1 = colBase + 16 + r;
  bool v0 = row0 < Mr, v1 = row1 < Mr;
  const __bf16* a0p = A + (size_t)row0 * K + kg * 8;
  const __bf16* a1p = A + (size_t)row1 * K + kg * 8;
  const __bf16* b0p = Bt + (size_t)col0 * K + kg * 8;
  const __bf16* b1p = Bt + (size_t)col1 * K + kg * 8;

  f32x4 acc[2][2];
  #pragma unroll
  for (int i = 0; i < 2; i++)
    #pragma unroll
    for (int j = 0; j < 2; j++) { acc[i][j][0] = 0.f; acc[i][j][1] = 0.f; acc[i][j][2] = 0.f; acc[i][j][3] = 0.f; }

  for (int k0 = 0; k0 < K; k0 += 32) {
    bf16x8 a0 = v0 ? ldb8(a0p + k0) : zerob8();
    bf16x8 a1 = v1 ? ldb8(a1p + k0) : zerob8();
    bf16x8 b0 = ldb8(b0p + k0);
    bf16x8 b1 = ldb8(b1p + k0);
    acc[0][0] = mfma16(a0, b0, acc[0][0]);
    acc[0][1] = mfma16(a0, b1, acc[0][1]);
    acc[1][0] = mfma16(a1, b0, acc[1][0]);
    acc[1][1] = mfma16(a1, b1, acc[1][1]);
  }

  #pragma unroll
  for (int i = 0; i < 2; i++) {
    #pragma unroll
    for (int g = 0; g < 4; g++) {
      int row = rowBase + i * 16 + kg * 4 + g;
      if (row >= Mr) continue;
      #pragma unroll
      for (int j = 0; j < 2; j++) {
        int col = colBase + j * 16 + r;
        C[(size_t)row * N + col] = acc[i][j][g] + bias[col];
      }
    }
  }
}

// sum split-K partials + bias + relu -> q (fp32) and qb (bf16, prescaled log2 e)
__global__ void fc_reduce(const float* __restrict__ part, const float* __restrict__ bias,
                          float* __restrict__ q, __bf16* __restrict__ qb, int nrows)
{
  int idx = blockIdx.x * 256 + threadIdx.x;       // nrows * H
  if (idx >= nrows * H) return;
  int col = idx & 255;
  float s = bias[col];
  for (int z = 0; z < FSPLIT; z++) s += part[(size_t)z * nrows * H + idx];
  s = fmaxf(s, 0.f);
  q[idx] = s;
  qb[idx] = (__bf16)(s * 1.44269504f);
}

// ------------------------- conv (block per test row) -----------------------
__global__ void conv_feat(const float* __restrict__ ent, const float* __restrict__ rel,
                          const float* __restrict__ sent, const int* __restrict__ tt,
                          const float* __restrict__ cw, const float* __restrict__ cb,
                          __bf16* __restrict__ out, int row0)
{
  __shared__ float f[3][258];
  __shared__ float wsm[CH * 9];
  __shared__ float bsm[CH];
  int i = row0 + blockIdx.x;
  int h = threadIdx.x;
  int j = (i < NT) ? i : i - NT;
  int a0 = (i < NT) ? tt[j * 3 + 0] : tt[j * 3 + 2];
  int a1 = (i < NT) ? tt[j * 3 + 1] : tt[j * 3 + 1] + NR;
  f[0][h + 1] = ent[(size_t)a0 * H + h];
  f[1][h + 1] = rel[(size_t)a1 * H + h];
  f[2][h + 1] = sent[(size_t)j * H + h];
  if (h < 3) { f[h][0] = 0.f; f[h][257] = 0.f; }
  for (int x = h; x < CH * 9; x += 256) wsm[x] = cw[x];
  if (h < CH) bsm[h] = cb[h];
  __syncthreads();
  __bf16* orow = out + (size_t)blockIdx.x * KFC;
  for (int c = 0; c < CH; c++) {
    const float* wc = wsm + c * 9;
    float s = bsm[c];
    #pragma unroll
    for (int ic = 0; ic < 3; ic++)
      s += wc[ic * 3 + 0] * f[ic][h] + wc[ic * 3 + 1] * f[ic][h + 1] + wc[ic * 3 + 2] * f[ic][h + 2];
    orow[(size_t)c * H + h] = (__bf16)fmaxf(s, 0.f);
  }
}

// one wave per row: nll[row] = log(sum_c part_l - PADCOLS) - q[row].ent[tgt]
__global__ void lse_combine(const float* __restrict__ part_l, const float* __restrict__ qf,
                            const float* __restrict__ ent, const int* __restrict__ tt,
                            float* __restrict__ nll)
{
  int gid = blockIdx.x * 256 + threadIdx.x;
  int w = gid >> 6;
  if (w >= NT2) return;
  int lane = gid & 63;
  int j = (w < NT) ? w : w - NT;
  int tgt = (w < NT) ? tt[j * 3 + 2] : tt[j * 3 + 0];
  const float4 qa = ((const float4*)(qf + (size_t)w * H))[lane];
  const float4 ea = ((const float4*)(ent + (size_t)tgt * H))[lane];
  float d = qa.x * ea.x + qa.y * ea.y + qa.z * ea.z + qa.w * ea.w;
  float s = (lane < NCHUNK) ? part_l[(size_t)lane * ROWPAD + w] : 0.f;
  #pragma unroll
  for (int o = 32; o > 0; o >>= 1) {
    d += __shfl_down(d, o, 64);
    s += __shfl_down(s, o, 64);
  }
  if (lane == 0) nll[w] = logf(s - PADCOLS) - d;
}

__global__ void mean_nll(const float* __restrict__ nll, float* __restrict__ out)
{
  float s = 0.f;
  for (int i = threadIdx.x; i < NT2; i += 256) s += nll[i];
  s = block_sum256(s);
  if (threadIdx.x == 0) out[0] = s * (1.f / NT2);
}

// ------------------------- launcher ----------------------------------------
extern "C" void kernel_launch(void* const* d_in, const int* in_sizes, int n_in,
                              void* d_out, int out_size, void* d_ws, size_t ws_size,
                              hipStream_t stream)
{
  const float* dynamic_emb = (const float*)d_in[0];
  const float* emb_rel     = (const float*)d_in[1];
  const float* gru_W_ih    = (const float*)d_in[2];
  const float* gru_W_hh    = (const float*)d_in[3];
  const float* gru_b_ih    = (const float*)d_in[4];
  const float* gru_b_hh    = (const float*)d_in[5];
  const float* agg_W       = (const float*)d_in[6];
  const float* tg_W        = (const float*)d_in[7];
  const float* tg_b        = (const float*)d_in[8];
  const float* hev         = (const float*)d_in[9];
  const float* hrv         = (const float*)d_in[10];
  const float* conv_w      = (const float*)d_in[11];
  const float* conv_b      = (const float*)d_in[12];
  const float* fc_W        = (const float*)d_in[13];
  const float* fc_b        = (const float*)d_in[14];
  const float* sent        = (const float*)d_in[15];
  const int* edge_src = (const int*)d_in[16];
  const int* edge_rel = (const int*)d_in[17];
  const int* edge_dst = (const int*)d_in[18];
  const int* r_to_e   = (const int*)d_in[19];
  const int* r_ids    = (const int*)d_in[20];
  const int* he_row   = (const int*)d_in[21];
  const int* he_col   = (const int*)d_in[22];
  const int* hr_row   = (const int*)d_in[23];
  const int* hr_col   = (const int*)d_in[24];
  const int* tt       = (const int*)d_in[25];
  float* out = (float*)d_out;

  char* base = (char*)d_ws;
  size_t off = 0;
  auto alloc = [&](size_t bytes) { char* p = base + off; off += (bytes + 255) & ~(size_t)255; return p; };

  float* ent    = (float*)alloc((size_t)NE * H * 4);
  float* curr   = (float*)alloc((size_t)NE * H * 4);   // hyper ping-pong; conv_bf overlay
  float* tgbuf  = (float*)alloc((size_t)NE * H * 4);
  __bf16* convb = (__bf16*)curr;                        // 1600*12800*2 = 40.96 MB spans curr+tgbuf
  __bf16* entb  = (__bf16*)alloc((size_t)NE * H * 2);
  __bf16* entb2 = (__bf16*)alloc((size_t)NE * H * 2);
  __bf16* accEb = (__bf16*)alloc((size_t)NE * H * 2);
  __bf16* ebf   = (__bf16*)alloc((size_t)NEPAD * H * 2);   // frag-packed ent
  __bf16* qbf   = (__bf16*)alloc((size_t)ROWPAD * H * 2);  // frag-packed q
  float* rel    = (float*)alloc((size_t)R2 * H * 4);
  float* accR   = (float*)alloc((size_t)R2 * H * 4);
  __bf16* relb  = (__bf16*)alloc((size_t)R2 * H * 2);
  __bf16* xinb  = (__bf16*)alloc((size_t)R2 * 2 * H * 2);
  float* gi     = (float*)alloc((size_t)R2 * H3 * 4);
  float* gh     = (float*)alloc((size_t)R2 * H3 * 4);
  float* qf     = (float*)alloc((size_t)NT2 * H * 4);
  __bf16* qb    = (__bf16*)alloc((size_t)NT2 * H * 2);
  float* part_l = (float*)alloc((size_t)NCHUNK * ROWPAD * 4);
  float* partM  = (float*)alloc((size_t)R2 * MSPLIT * H * 4);
  float* fcpart = (float*)alloc((size_t)FSPLIT * 1600 * H * 4);   // 32.8 MB
  float* nll    = (float*)alloc((size_t)NT2 * 4);
  __bf16* tgWtb = (__bf16*)alloc((size_t)H * H * 2);
  __bf16* aggWtb= (__bf16*)alloc((size_t)H * H * 2);
  __bf16* fcWtb = (__bf16*)alloc((size_t)H * KFC * 2);
  __bf16* Wihb  = (__bf16*)alloc((size_t)H3 * 2 * H * 2);
  __bf16* Whhb  = (__bf16*)alloc((size_t)H3 * H * 2);

  int* ip = (int*)alloc(0);
  size_t ioff = 0;
  auto ialloc = [&](size_t n) { int* p = ip + ioff; ioff += n; return p; };
  int* fidxM[TT];
  int2* fsrE[TT];
  for (int t = 0; t < TT; t++) fidxM[t] = ialloc(M);
  for (int t = 0; t < TT; t++) fsrE[t] = (int2*)ialloc((size_t)NEDGE * 2);
  int2* fcvHE = (int2*)ialloc((size_t)NNZ_E * 2);
  int2* fcvHR = (int2*)ialloc((size_t)NNZ_R * 2);
  int* cnt_all    = ialloc(CNT_TOTAL);
  int* start_all  = ialloc(CNT_TOTAL);
  int* cursor_all = ialloc(CNT_TOTAL);
  int* bcnt  = ialloc((size_t)4 * NB_CS * 512);
  int* bbase = ialloc((size_t)4 * NB_CS * 512);
  int* bsumNE = ialloc((size_t)4 * NB_NE);

  int* sM[TT];  for (int t = 0; t < TT; t++) sM[t] = start_all + t * 512;
  int* sHR = start_all + 1536;
  int* sE[TT];  for (int t = 0; t < TT; t++) sE[t] = start_all + CNT_NE_BASE + t * CNT_NE_STRIDE;
  int* sHE = start_all + CNT_NE_BASE + 3 * CNT_NE_STRIDE;

  // --- weight prep (bf16) ---
  transpose_cast_k<<<dim3(H / 32, H / 32), 256, 0, stream>>>(tg_W, tgWtb, H, H);
  transpose_cast_k<<<dim3(H / 32, H / 32), 256, 0, stream>>>(agg_W, aggWtb, H, H);
  transpose_cast_k<<<dim3(KFC / 32, H / 32), 256, 0, stream>>>(fc_W, fcWtb, KFC, H);
  cast_bf16_k<<<(H3 * 2 * H / 8 + 255) / 256, 256, 0, stream>>>(gru_W_ih, Wihb, H3 * 2 * H / 8);
  cast_bf16_k<<<(H3 * H / 8 + 255) / 256, 256, 0, stream>>>(gru_W_hh, Whhb, H3 * H / 8);

  // --- CSR build: counting-sort for R2-keyed arrays ---
  cs_hist_k<<<dim3(NB_CS, 4), 256, 0, stream>>>(r_ids, hr_row, bcnt);
  cs_scan_k<<<4, 256, 0, stream>>>(bcnt, bbase, start_all);
  cs_scatter_k<<<dim3(NB_CS, 4), 256, 0, stream>>>(r_ids, r_to_e, hr_row, hr_col, hrv, bbase,
                                                   fidxM[0], fidxM[1], fidxM[2], fcvHR);

  // --- CSR build: NE-keyed arrays (parallel 3-phase scan) ---
  hipMemsetAsync(cnt_all + CNT_NE_BASE, 0, (size_t)(CNT_TOTAL - CNT_NE_BASE) * 4, stream);
  hist_ne_k<<<dim3((NNZ_E + 255) / 256, 4), 256, 0, stream>>>(edge_dst, he_row, cnt_all);
  scan_ne1_k<<<dim3(NB_NE, 4), 256, 0, stream>>>(cnt_all, start_all, bsumNE);
  scan_ne2_k<<<4, 256, 0, stream>>>(bsumNE, start_all);
  scan_ne3_k<<<dim3(NB_NE, 4), 256, 0, stream>>>(start_all, cursor_all, bsumNE);
  perm_fuse2i_k<<<dim3((NEDGE + 255) / 256, 3), 256, 0, stream>>>(
      edge_dst, edge_src, edge_rel, cursor_all, fsrE[0], fsrE[1], fsrE[2]);
  perm_fusevi_k<<<(NNZ_E + 255) / 256, 256, 0, stream>>>(
      he_row, he_col, hev, NNZ_E, cursor_all + CNT_NE_BASE + 3 * CNT_NE_STRIDE, fcvHE);

  constexpr int NEH8 = NE * H / 8, R2H8 = R2 * H / 8;
  constexpr int NE_RB = (NE + 127) / 128;   // 157

  // fused copy + bf16 cast
  copy_cast_k<<<(NEH8 + 255) / 256, 256, 0, stream>>>(dynamic_emb, ent, entb, NEH8);
  copy_cast_k<<<(R2H8 + 255) / 256, 256, 0, stream>>>(emb_rel, rel, relb, R2H8);

  for (int t = 0; t < TT; t++) {
    // --- rel update (GRU) ---
    gather_mean2_k<<<dim3(R2, MSPLIT), 256, 0, stream>>>(entb, fidxM[t], sM[t], partM);
    mean_xin_k<<<R2, 256, 0, stream>>>(partM, sM[t], rel, xinb);
    gru_gemm2_k<<<dim3(H3 / 64, (R2 + 63) / 64, 2), 256, 0, stream>>>(
        xinb, relb, Wihb, Whhb, gru_b_ih, gru_b_hh, gi, gh);
    gru_combine<<<(R2 * H + 255) / 256, 256, 0, stream>>>(gi, gh, rel, relb);

    // --- ent update: gate, gather, agg+blend (fused) ---
    panel2_gemm<2><<<dim3(4, NE_RB), 256, 0, stream>>>(
        entb, tgWtb, tg_b, tgbuf, NE, H, nullptr, nullptr, nullptr);
    gather_edges3_k<<<NE, 256, 0, stream>>>(entb, relb, fsrE[t], sE[t], accEb);
    panel2_gemm<4><<<dim3(4, NE_RB), 256, 0, stream>>>(
        accEb, aggWtb, nullptr, nullptr, NE, H, tgbuf, ent, entb);
  }

  // --- hypergraph layers ---
  hyper3_k<<<NE, 256, 0, stream>>>(ent, entb, fcvHE, sHE, curr, entb2);
  hyper3_k<<<NE, 256, 0, stream>>>(curr, entb2, fcvHE, sHE, ent, entb);
  hyper_rel_k<<<R2, 256, 0, stream>>>(rel, fcvHR, sHR, accR);
  hyper_rel_k<<<R2, 256, 0, stream>>>(accR, fcvHR, sHR, rel);

  // frag-pack final ent for scores B
  pack_frag_k<<<(NEPAD * 32 + 255) / 256, 256, 0, stream>>>(entb, ebf, NEPAD * 32, NE);

  // --- conv + fc (3 chunks: 1600, 1600, 800 rows) ---
  for (int c = 0; c < 3; c++) {
    int row0 = c * 1600;
    int rows = min(1600, NT2 - row0);
    conv_feat<<<rows, 256, 0, stream>>>(ent, rel, sent, tt, conv_w, conv_b, convb, row0);
    fc_gemm<<<dim3(FSPLIT, (rows + 127) / 128), 256, 0, stream>>>(convb, fcWtb, fcpart, rows);
    fc_reduce<<<(rows * H + 255) / 256, 256, 0, stream>>>(
        fcpart, fc_b, qf + (size_t)row0 * H, qb + (size_t)row0 * H, rows);
  }

  // frag-pack q for scores A
  pack_frag_k<<<(ROWPAD * 32 + 255) / 256, 256, 0, stream>>>(qb, qbf, ROWPAD * 32, NT2);

  // --- fused scores + LSE: 32 chunks x 32 row-blocks, 20 panels each ---
  scores_v4<<<dim3(NCHUNK, 32), 256, 0, stream>>>(qbf, ebf, part_l);
  lse_combine<<<(NT2 * 64 + 255) / 256, 256, 0, stream>>>(part_l, qf, ent, tt, nll);
  mean_nll<<<1, 256, 0, stream>>>(nll, out);
}

// Round 14
// 775.006 us; speedup vs baseline: 1.2368x; 1.0339x over previous
//
#include <hip/hip_runtime.h>
#include <math.h>

#define DEV_INLINE __device__ __forceinline__

constexpr int H      = 256;
constexpr int NE     = 20000;
constexpr int NR     = 250;
constexpr int R2     = 500;
constexpr int TT     = 3;
constexpr int NEDGE  = 150000;
constexpr int M      = 200000;
constexpr int NNZ_E  = 320000;
constexpr int NNZ_R  = 8000;
constexpr int CH     = 50;
constexpr int NT     = 2000;
constexpr int NT2    = 4000;
constexpr int H3     = 3 * H;     // 768
constexpr int KFC    = CH * H;    // 12800
constexpr int ROWPAD = 4096;
constexpr int NCHUNK = 32;        // scores col chunks
constexpr int SPP    = 20;        // 32-col panels per chunk (scores_v4)
constexpr int MSPLIT = 8;         // gather_mean row split
constexpr int FSPLIT = 20;        // fc split-K
constexpr int NB_CS  = 64;        // counting-sort blocks per R2 array
constexpr int NEPAD  = 20480;     // ent rows padded to 64
constexpr int NB_NE  = 80;        // NE-scan blocks per array
constexpr float PADCOLS = 480.f;  // NEPAD - NE: exp2(0) contributions to subtract

// cnt/start/cursor packed region (ints)
constexpr int CNT_NE_BASE   = 2048;
constexpr int CNT_NE_STRIDE = 20224;
constexpr int CNT_TOTAL     = CNT_NE_BASE + 4 * CNT_NE_STRIDE;  // 82944

typedef __bf16 bf16x8 __attribute__((ext_vector_type(8)));
typedef float  f32x4  __attribute__((ext_vector_type(4)));

DEV_INLINE bf16x8 ldb8(const __bf16* p) { return *(const bf16x8*)p; }
DEV_INLINE bf16x8 zerob8() { uint4 z = make_uint4(0, 0, 0, 0); return __builtin_bit_cast(bf16x8, z); }
DEV_INLINE f32x4 mfma16(bf16x8 a, bf16x8 b, f32x4 c) {
  return __builtin_amdgcn_mfma_f32_16x16x32_bf16(a, b, c, 0, 0, 0);
}
DEV_INLINE void gload_lds16(const void* g, void* l) {
  __builtin_amdgcn_global_load_lds((const __attribute__((address_space(1))) void*)g,
                                   (__attribute__((address_space(3))) void*)l, 16, 0, 0);
}

// ------------------------- block reduction (blockDim == 256) ---------------
DEV_INLINE float block_sum256(float v) {
  __shared__ float ws[4];
  #pragma unroll
  for (int o = 32; o > 0; o >>= 1) v += __shfl_down(v, o, 64);
  if ((threadIdx.x & 63) == 0) ws[threadIdx.x >> 6] = v;
  __syncthreads();
  float r = ws[0] + ws[1] + ws[2] + ws[3];
  __syncthreads();
  return r;
}

// ------------------- counting-sort CSR (R2-keyed arrays) -------------------
__global__ void cs_hist_k(const int* __restrict__ r_ids, const int* __restrict__ hr_row,
                          int* __restrict__ bcnt)
{
  __shared__ int lh[512];
  int a = blockIdx.y;
  const int* keys = (a < 3) ? r_ids + (size_t)a * M : hr_row;
  int n = (a < 3) ? M : NNZ_R;
  int t = threadIdx.x;
  lh[t] = 0; lh[t + 256] = 0;
  __syncthreads();
  int chunk = (n + NB_CS - 1) / NB_CS;
  int i0 = blockIdx.x * chunk, i1 = min(i0 + chunk, n);
  for (int i = i0 + t; i < i1; i += 256) atomicAdd(&lh[keys[i]], 1);
  __syncthreads();
  int* outp = bcnt + ((size_t)a * NB_CS + blockIdx.x) * 512;
  outp[t] = lh[t]; outp[t + 256] = lh[t + 256];
}

__global__ void cs_scan_k(const int* __restrict__ bcnt, int* __restrict__ bbase,
                          int* __restrict__ start_all)
{
  __shared__ int ps[257];
  int a = blockIdx.x;
  int* start = start_all + ((a < 3) ? a * 512 : 1536);
  const int* bc = bcnt + (size_t)a * NB_CS * 512;
  int* bb = bbase + (size_t)a * NB_CS * 512;
  int t = threadIdx.x;
  int b0 = 2 * t, b1 = 2 * t + 1;
  int tot0 = 0, tot1 = 0;
  for (int blk = 0; blk < NB_CS; blk++) {
    tot0 += bc[blk * 512 + b0];
    tot1 += bc[blk * 512 + b1];
  }
  ps[t + 1] = tot0 + tot1;
  if (t == 0) ps[0] = 0;
  __syncthreads();
  if (t == 0) { for (int i = 1; i <= 256; i++) ps[i] += ps[i - 1]; }
  __syncthreads();
  int run0 = ps[t], run1 = ps[t] + tot0;
  start[b0] = run0;
  start[b1] = run1;
  for (int blk = 0; blk < NB_CS; blk++) {
    bb[blk * 512 + b0] = run0; run0 += bc[blk * 512 + b0];
    bb[blk * 512 + b1] = run1; run1 += bc[blk * 512 + b1];
  }
}

__global__ void cs_scatter_k(const int* __restrict__ r_ids, const int* __restrict__ r_to_e,
                             const int* __restrict__ hr_row, const int* __restrict__ hr_col,
                             const float* __restrict__ hrv, const int* __restrict__ bbase,
                             int* __restrict__ f0, int* __restrict__ f1, int* __restrict__ f2,
                             int2* __restrict__ fcvHR)
{
  __shared__ int cur[512];
  int a = blockIdx.y;
  const int* keys = (a < 3) ? r_ids + (size_t)a * M : hr_row;
  int n = (a < 3) ? M : NNZ_R;
  int t = threadIdx.x;
  const int* bb = bbase + ((size_t)a * NB_CS + blockIdx.x) * 512;
  cur[t] = bb[t]; cur[t + 256] = bb[t + 256];
  __syncthreads();
  int chunk = (n + NB_CS - 1) / NB_CS;
  int i0 = blockIdx.x * chunk, i1 = min(i0 + chunk, n);
  if (a < 3) {
    const int* other = r_to_e + (size_t)a * M;
    int* f = (a == 0) ? f0 : (a == 1) ? f1 : f2;
    for (int i = i0 + t; i < i1; i += 256) {
      int p = atomicAdd(&cur[keys[i]], 1);
      f[p] = other[i];
    }
  } else {
    for (int i = i0 + t; i < i1; i += 256) {
      int p = atomicAdd(&cur[keys[i]], 1);
      fcvHR[p] = make_int2(hr_col[i], __float_as_int(hrv[i]));
    }
  }
}

// ------------------- NE-keyed CSR (low contention) -------------------------
__global__ void hist_ne_k(const int* __restrict__ edge_dst, const int* __restrict__ he_row,
                          int* __restrict__ cnt_all)
{
  int a = blockIdx.y;
  const int* keys = (a < 3) ? edge_dst + (size_t)a * NEDGE : he_row;
  int n = (a < 3) ? NEDGE : NNZ_E;
  int* cnt = cnt_all + CNT_NE_BASE + a * CNT_NE_STRIDE;
  int i = blockIdx.x * 256 + threadIdx.x;
  if (i < n) atomicAdd(&cnt[keys[i]], 1);
}

__global__ void scan_ne1_k(const int* __restrict__ cnt_all, int* __restrict__ start_all,
                           int* __restrict__ bsum)
{
  __shared__ int wtot[4];
  int a = blockIdx.y;
  int off = CNT_NE_BASE + a * CNT_NE_STRIDE;
  int bin = blockIdx.x * 256 + threadIdx.x;
  int lane = threadIdx.x & 63, w = threadIdx.x >> 6;
  int v = (bin < NE) ? cnt_all[off + bin] : 0;
  int orig = v;
  #pragma unroll
  for (int o = 1; o < 64; o <<= 1) {
    int n = __shfl_up(v, o, 64);
    if (lane >= o) v += n;
  }
  if (lane == 63) wtot[w] = v;
  __syncthreads();
  int wo = 0;
  #pragma unroll
  for (int i = 0; i < 4; i++) if (i < w) wo += wtot[i];
  if (bin < NE) start_all[off + bin] = v - orig + wo;
  if (threadIdx.x == 255) bsum[a * NB_NE + blockIdx.x] = wo + v;
}

__global__ void scan_ne2_k(int* __restrict__ bsum, int* __restrict__ start_all)
{
  __shared__ int s[NB_NE + 1];
  int a = blockIdx.x;
  int t = threadIdx.x;
  if (t < NB_NE) s[t + 1] = bsum[a * NB_NE + t];
  if (t == 0) s[0] = 0;
  __syncthreads();
  if (t == 0) { for (int i = 1; i <= NB_NE; i++) s[i] += s[i - 1]; }
  __syncthreads();
  if (t < NB_NE) bsum[a * NB_NE + t] = s[t];
  if (t == 0) start_all[CNT_NE_BASE + a * CNT_NE_STRIDE + NE] = s[NB_NE];
}

__global__ void scan_ne3_k(int* __restrict__ start_all, int* __restrict__ cursor_all,
                           const int* __restrict__ bsum)
{
  int a = blockIdx.y;
  int off = CNT_NE_BASE + a * CNT_NE_STRIDE;
  int bin = blockIdx.x * 256 + threadIdx.x;
  if (bin >= NE) return;
  int v = start_all[off + bin] + bsum[a * NB_NE + blockIdx.x];
  start_all[off + bin] = v;
  cursor_all[off + bin] = v;
}

// batched: 3 edge arrays in one launch (grid.y = 3)
__global__ void perm_fuse2i_k(const int* __restrict__ edge_dst, const int* __restrict__ edge_src,
                              const int* __restrict__ edge_rel, int* __restrict__ cursor_all,
                              int2* __restrict__ f0, int2* __restrict__ f1, int2* __restrict__ f2)
{
  int a = blockIdx.y;
  const int* keys = edge_dst + (size_t)a * NEDGE;
  const int* o1 = edge_src + (size_t)a * NEDGE;
  const int* o2 = edge_rel + (size_t)a * NEDGE;
  int* cursor = cursor_all + CNT_NE_BASE + a * CNT_NE_STRIDE;
  int2* f = (a == 0) ? f0 : (a == 1) ? f1 : f2;
  int i = blockIdx.x * 256 + threadIdx.x;
  if (i < NEDGE) { int p = atomicAdd(&cursor[keys[i]], 1); f[p] = make_int2(o1[i], o2[i]); }
}
__global__ void perm_fusevi_k(const int* __restrict__ keys, const int* __restrict__ col,
                              const float* __restrict__ val, int n, int* __restrict__ cursor,
                              int2* __restrict__ f)
{
  int i = blockIdx.x * 256 + threadIdx.x;
  if (i < n) {
    int p = atomicAdd(&cursor[keys[i]], 1);
    f[p] = make_int2(col[i], __float_as_int(val[i]));
  }
}

// ------------------------- casts / transposes ------------------------------
__global__ void cast_bf16_k(const float* __restrict__ in, __bf16* __restrict__ out, int n8)
{
  int i = blockIdx.x * 256 + threadIdx.x;
  if (i >= n8) return;
  const float4* p = (const float4*)in + (size_t)i * 2;
  float4 u = p[0], v = p[1];
  bf16x8 o;
  o[0] = (__bf16)u.x; o[1] = (__bf16)u.y; o[2] = (__bf16)u.z; o[3] = (__bf16)u.w;
  o[4] = (__bf16)v.x; o[5] = (__bf16)v.y; o[6] = (__bf16)v.z; o[7] = (__bf16)v.w;
  ((bf16x8*)out)[i] = o;
}

// copy fp32 + emit bf16 in one pass
__global__ void copy_cast_k(const float* __restrict__ in, float* __restrict__ outf,
                            __bf16* __restrict__ outb, int n8)
{
  int i = blockIdx.x * 256 + threadIdx.x;
  if (i >= n8) return;
  const float4* p = (const float4*)in + (size_t)i * 2;
  float4 u = p[0], v = p[1];
  ((float4*)outf)[(size_t)i * 2]     = u;
  ((float4*)outf)[(size_t)i * 2 + 1] = v;
  bf16x8 o;
  o[0] = (__bf16)u.x; o[1] = (__bf16)u.y; o[2] = (__bf16)u.z; o[3] = (__bf16)u.w;
  o[4] = (__bf16)v.x; o[5] = (__bf16)v.y; o[6] = (__bf16)v.z; o[7] = (__bf16)v.w;
  ((bf16x8*)outb)[i] = o;
}

__global__ void transpose_cast_k(const float* __restrict__ in, __bf16* __restrict__ out,
                                 int K, int N)
{
  __shared__ float tile[32][33];
  int tx = threadIdx.x & 31, ty = threadIdx.x >> 5;   // 32 x 8
  int kb = blockIdx.x * 32, nb = blockIdx.y * 32;
  #pragma unroll
  for (int i = 0; i < 4; i++)
    tile[ty + i * 8][tx] = in[(size_t)(kb + ty + i * 8) * N + nb + tx];
  __syncthreads();
  #pragma unroll
  for (int i = 0; i < 4; i++)
    out[(size_t)(nb + ty + i * 8) * K + kb + tx] = (__bf16)tile[tx][ty + i * 8];
}

// reorder [rows][256] bf16 into MFMA-frag-linear layout
__global__ void pack_frag_k(const __bf16* __restrict__ src, __bf16* __restrict__ dst,
                            int nchunks, int Mr)
{
  int i = blockIdx.x * 256 + threadIdx.x;
  if (i >= nchunks) return;
  int c = i >> 5, s = i & 31;
  bf16x8 v = (c < Mr) ? ldb8(src + (size_t)c * H + s * 8) : zerob8();
  int kf = s >> 2, kg = s & 3;
  size_t d = ((((size_t)(c >> 6) * 4 + ((c >> 4) & 3)) * 8 + kf) * 4 + kg) * 16 + (c & 15);
  *(bf16x8*)(dst + d * 8) = v;
}

// ------------------------- gather kernels (16 B/lane, 32-lane halves) ------
__global__ void gather_mean2_k(const __bf16* __restrict__ src, const int* __restrict__ fidx,
                               const int* __restrict__ start, float* __restrict__ part)
{
  __shared__ __align__(16) float red[4][H];
  int r = blockIdx.x, s = blockIdx.y;
  int s0 = start[r], s1 = start[r + 1];
  int len = s1 - s0;
  int chunk = (len + MSPLIT - 1) / MSPLIT;
  int jb = s0 + s * chunk, je = min(jb + chunk, s1);
  int tid = threadIdx.x, lane = tid & 63, w = tid >> 6;
  int half = lane >> 5, l = lane & 31;
  float acc[8] = {0.f, 0.f, 0.f, 0.f, 0.f, 0.f, 0.f, 0.f};
  for (int j = jb + w * 2 + half; j < je; j += 8) {
    int e = fidx[j];
    bf16x8 v = ldb8(src + (size_t)e * H + l * 8);
    #pragma unroll
    for (int q = 0; q < 8; q++) acc[q] += (float)v[q];
  }
  #pragma unroll
  for (int q = 0; q < 8; q++) acc[q] += __shfl_xor(acc[q], 32, 64);
  if (half == 0) {
    *(float4*)&red[w][l * 8]     = make_float4(acc[0], acc[1], acc[2], acc[3]);
    *(float4*)&red[w][l * 8 + 4] = make_float4(acc[4], acc[5], acc[6], acc[7]);
  }
  __syncthreads();
  int h = tid;
  part[((size_t)r * MSPLIT + s) * H + h] = red[0][h] + red[1][h] + red[2][h] + red[3][h];
}

__global__ void mean_xin_k(const float* __restrict__ partM, const int* __restrict__ start,
                           const float* __restrict__ rel, __bf16* __restrict__ xin)
{
  int r = blockIdx.x, h = threadIdx.x;
  float s = 0.f;
  #pragma unroll
  for (int z = 0; z < MSPLIT; z++) s += partM[((size_t)r * MSPLIT + z) * H + h];
  float xm = s / (float)max(start[r + 1] - start[r], 1);
  xin[(size_t)r * 2 * H + h]     = (__bf16)rel[(size_t)r * H + h];
  xin[(size_t)r * 2 * H + H + h] = (__bf16)xm;
}

__global__ void gather_edges3_k(const __bf16* __restrict__ ent, const __bf16* __restrict__ rel,
                                const int2* __restrict__ fsr,
                                const int* __restrict__ start, __bf16* __restrict__ out)
{
  __shared__ __align__(16) float red[4][H];
  int d = blockIdx.x;
  int s0 = start[d], s1 = start[d + 1];
  int tid = threadIdx.x, lane = tid & 63, w = tid >> 6;
  int half = lane >> 5, l = lane & 31;
  const __bf16* srcbase = half ? rel : ent;
  float acc[8] = {0.f, 0.f, 0.f, 0.f, 0.f, 0.f, 0.f, 0.f};
  for (int j = s0 + w; j < s1; j += 4) {
    int2 e2 = fsr[j];
    int e = half ? e2.y : e2.x;
    bf16x8 v = ldb8(srcbase + (size_t)e * H + l * 8);
    #pragma unroll
    for (int q = 0; q < 8; q++) acc[q] += (float)v[q];
  }
  #pragma unroll
  for (int q = 0; q < 8; q++) acc[q] += __shfl_xor(acc[q], 32, 64);
  if (half == 0) {
    *(float4*)&red[w][l * 8]     = make_float4(acc[0], acc[1], acc[2], acc[3]);
    *(float4*)&red[w][l * 8 + 4] = make_float4(acc[4], acc[5], acc[6], acc[7]);
  }
  __syncthreads();
  int h = tid;
  float sum = red[0][h] + red[1][h] + red[2][h] + red[3][h];
  out[(size_t)d * H + h] = (__bf16)(sum / (float)max(s1 - s0, 1));
}

__global__ void hyper3_k(const float* __restrict__ x, const __bf16* __restrict__ xb,
                         const int2* __restrict__ fcv,
                         const int* __restrict__ start,
                         float* __restrict__ xout, __bf16* __restrict__ xoutb)
{
  __shared__ __align__(16) float red[4][H];
  int r = blockIdx.x;
  int s0 = start[r], s1 = start[r + 1];
  int tid = threadIdx.x, lane = tid & 63, w = tid >> 6;
  int half = lane >> 5, l = lane & 31;
  float acc[8] = {0.f, 0.f, 0.f, 0.f, 0.f, 0.f, 0.f, 0.f};
  for (int j = s0 + w * 2 + half; j < s1; j += 8) {
    int2 cv = fcv[j];
    float wt = __int_as_float(cv.y);
    bf16x8 v = ldb8(xb + (size_t)cv.x * H + l * 8);
    #pragma unroll
    for (int q = 0; q < 8; q++) acc[q] += wt * (float)v[q];
  }
  #pragma unroll
  for (int q = 0; q < 8; q++) acc[q] += __shfl_xor(acc[q], 32, 64);
  if (half == 0) {
    *(float4*)&red[w][l * 8]     = make_float4(acc[0], acc[1], acc[2], acc[3]);
    *(float4*)&red[w][l * 8 + 4] = make_float4(acc[4], acc[5], acc[6], acc[7]);
  }
  __syncthreads();
  int h = tid;
  float y = red[0][h] + red[1][h] + red[2][h] + red[3][h];
  float ss = block_sum256(y * y);
  float rn = 1.f / fmaxf(sqrtf(ss), 1e-12f);
  float o = x[(size_t)r * H + h] + y * rn;
  xout[(size_t)r * H + h] = o;
  xoutb[(size_t)r * H + h] = (__bf16)o;
}

__global__ void hyper_rel_k(const float* __restrict__ x, const int2* __restrict__ fcv,
                            const int* __restrict__ start, float* __restrict__ xout)
{
  int r = blockIdx.x, h = threadIdx.x;
  int s0 = start[r], s1 = start[r + 1];
  float a0 = 0.f;
  for (int j = s0; j < s1; j++) {
    int2 cv = fcv[j];
    a0 += __int_as_float(cv.y) * x[(size_t)cv.x * H + h];
  }
  float ss = block_sum256(a0 * a0);
  float rn = 1.f / fmaxf(sqrtf(ss), 1e-12f);
  xout[(size_t)r * H + h] = x[(size_t)r * H + h] + a0 * rn;
}

// ------------------------- small elementwise -------------------------------
__global__ void gru_combine(const float* __restrict__ gi, const float* __restrict__ gh,
                            float* __restrict__ rel, __bf16* __restrict__ relb)
{
  int idx = blockIdx.x * 256 + threadIdx.x;       // R2 * H
  if (idx >= R2 * H) return;
  int i = idx >> 8, h = idx & 255;
  const float* gir = gi + (size_t)i * H3;
  const float* ghr = gh + (size_t)i * H3;
  float r = 1.f / (1.f + __expf(-(gir[h]       + ghr[h])));
  float z = 1.f / (1.f + __expf(-(gir[H + h]   + ghr[H + h])));
  float n = tanhf(gir[2 * H + h] + r * ghr[2 * H + h]);
  float o = (1.f - z) * n + z * rel[idx];
  rel[idx] = o;
  relb[idx] = (__bf16)o;
}

// ------------------------- panel2 GEMM (K=256, 64-col B panels) -------------
// staging via global_load_lds: linear LDS dest, pre-swizzled global source
DEV_INLINE void stage64_g(const __bf16* src, char* lds, int rowBase, int rowLimit, int tid)
{
  int lane = tid & 63;
  int wbase = (tid & ~63) * 16;   // wave * 1024
  #pragma unroll
  for (int q = 0; q < 8; q++) {
    int X = q * 4096 + wbase + lane * 16;
    int row = X >> 9, boff = X & 511;
    int soff = boff ^ ((row & 7) << 4);
    int grow = min(rowBase + row, rowLimit);
    gload_lds16((const char*)src + (size_t)grow * 512 + soff, lds + q * 4096 + wbase);
  }
}
DEV_INLINE bf16x8 frag64(const char* lds, int row, int kf, int kg)
{
  int off = (kf * 64 + kg * 16) ^ ((row & 7) << 4);
  return *(const bf16x8*)(lds + row * 512 + off);
}

// EPI: 2 = bias+sigmoid store to out; 4 = relu + gate-blend, writes entf/entbo
template<int EPI>
__global__ __launch_bounds__(256, 2) void panel2_gemm(const __bf16* __restrict__ A,
                                                      const __bf16* __restrict__ B,
                                                      const float* __restrict__ bias,
                                                      float* __restrict__ out,
                                                      int Mr, int N,
                                                      const float* __restrict__ gate,
                                                      float* __restrict__ entf,
                                                      __bf16* __restrict__ entbo)
{
  __shared__ __attribute__((aligned(16))) char lds0[32768];
  __shared__ __attribute__((aligned(16))) char lds1[32768];
  int tid = threadIdx.x;
  int lane = tid & 63, wM = tid >> 6;
  int r = lane & 15, kg = lane >> 4;
  int rowBase = blockIdx.y * 128;

  stage64_g(A, lds0, rowBase, Mr - 1, tid);
  stage64_g(A, lds1, rowBase + 64, Mr - 1, tid);
  __syncthreads();

  bf16x8 a[2][8];
  {
    int base = wM * 32;
    const char* ab = (base >= 64) ? lds1 : lds0;
    #pragma unroll
    for (int i = 0; i < 2; i++) {
      int ar = (base + i * 16 + r) & 63;
      #pragma unroll
      for (int kf = 0; kf < 8; kf++) a[i][kf] = frag64(ab, ar, kf, kg);
    }
  }
  __syncthreads();
  stage64_g(B, lds0, blockIdx.x * 64, N - 1, tid);
  __syncthreads();

  f32x4 acc[2][4];
  #pragma unroll
  for (int i = 0; i < 2; i++)
    #pragma unroll
    for (int j = 0; j < 4; j++) {
      acc[i][j][0] = 0.f; acc[i][j][1] = 0.f; acc[i][j][2] = 0.f; acc[i][j][3] = 0.f;
    }
  __builtin_amdgcn_s_setprio(1);
  #pragma unroll
  for (int kf = 0; kf < 8; kf++) {
    bf16x8 b[4];
    #pragma unroll
    for (int j = 0; j < 4; j++) b[j] = frag64(lds0, j * 16 + r, kf, kg);
    #pragma unroll
    for (int i = 0; i < 2; i++)
      #pragma unroll
      for (int j = 0; j < 4; j++)
        acc[i][j] = mfma16(a[i][kf], b[j], acc[i][j]);
  }
  __builtin_amdgcn_s_setprio(0);

  #pragma unroll
  for (int i = 0; i < 2; i++)
    #pragma unroll
    for (int g = 0; g < 4; g++) {
      int row = rowBase + wM * 32 + i * 16 + kg * 4 + g;
      if (row >= Mr) continue;
      #pragma unroll
      for (int j = 0; j < 4; j++) {
        int col = blockIdx.x * 64 + j * 16 + r;
        if (col >= N) continue;
        float v = acc[i][j][g];
        if (EPI == 2) {
          if (bias) v += bias[col];
          v = 1.f / (1.f + __expf(-v));
          out[(size_t)row * N + col] = v;
        } else {   // EPI == 4: relu + gate blend + dual store
          v = fmaxf(v, 0.f);
          size_t idx = (size_t)row * N + col;
          float t = gate[idx];
          float o = t * v + (1.f - t) * entf[idx];
          entf[idx] = o;
          entbo[idx] = (__bf16)o;
        }
      }
    }
}

// ------------------------- scores_v4 (frag-packed, 32-col panels) ----------
__global__ __launch_bounds__(256, 3) void scores_v4(const __bf16* __restrict__ qbf,
                                                    const __bf16* __restrict__ ebf,
                                                    float* __restrict__ part_l)
{
  __shared__ __attribute__((aligned(16))) char lds[2][16384];
  int tid = threadIdx.x, lane = tid & 63, w = tid >> 6;
  int r = lane & 15, kg = lane >> 4;

  auto stage = [&](int buf, int p) {
    const char* g = (const char*)ebf + ((size_t)(blockIdx.x * SPP + p)) * 16384;
    int wbase = (tid & ~63) * 16;
    #pragma unroll
    for (int q = 0; q < 4; q++) {
      int o = q * 4096 + wbase;
      gload_lds16(g + o + lane * 16, lds[buf] + o);
    }
  };

  stage(0, 0);

  bf16x8 a[2][8];
  {
    int cb = blockIdx.y * 2 + (w >> 1);
    int jb = (w & 1) * 2;
    const __bf16* ap = qbf + (size_t)cb * 16384 + kg * 128 + r * 8;
    #pragma unroll
    for (int i = 0; i < 2; i++)
      #pragma unroll
      for (int kf = 0; kf < 8; kf++)
        a[i][kf] = ldb8(ap + ((jb + i) * 8 + kf) * 512);
  }
  __syncthreads();

  float lsum[2][4];
  #pragma unroll
  for (int i = 0; i < 2; i++)
    #pragma unroll
    for (int g = 0; g < 4; g++) lsum[i][g] = 0.f;

  const char* l0 = lds[0] + kg * 256 + r * 16;
  const char* l1 = lds[1] + kg * 256 + r * 16;

  for (int p = 0; p < SPP; p++) {
    if (p + 1 < SPP) stage((p + 1) & 1, p + 1);
    const char* cur = (p & 1) ? l1 : l0;

    f32x4 acc[2][2];
    #pragma unroll
    for (int i = 0; i < 2; i++)
      #pragma unroll
      for (int j = 0; j < 2; j++) {
        acc[i][j][0] = 0.f; acc[i][j][1] = 0.f; acc[i][j][2] = 0.f; acc[i][j][3] = 0.f;
      }
    __builtin_amdgcn_s_setprio(1);
    #pragma unroll
    for (int kf = 0; kf < 8; kf++) {
      bf16x8 b0 = *(const bf16x8*)(cur + (0 * 8 + kf) * 1024);
      bf16x8 b1 = *(const bf16x8*)(cur + (1 * 8 + kf) * 1024);
      acc[0][0] = mfma16(a[0][kf], b0, acc[0][0]);
      acc[0][1] = mfma16(a[0][kf], b1, acc[0][1]);
      acc[1][0] = mfma16(a[1][kf], b0, acc[1][0]);
      acc[1][1] = mfma16(a[1][kf], b1, acc[1][1]);
    }
    __builtin_amdgcn_s_setprio(0);

    #pragma unroll
    for (int j = 0; j < 2; j++)
      #pragma unroll
      for (int i = 0; i < 2; i++)
        #pragma unroll
        for (int g = 0; g < 4; g++)
          lsum[i][g] += exp2f(acc[i][j][g]);
    __syncthreads();
  }

  #pragma unroll
  for (int m = 1; m < 16; m <<= 1)
    #pragma unroll
    for (int i = 0; i < 2; i++)
      #pragma unroll
      for (int g = 0; g < 4; g++)
        lsum[i][g] += __shfl_xor(lsum[i][g], m, 64);
  if (r == 0) {
    #pragma unroll
    for (int i = 0; i < 2; i++)
      #pragma unroll
      for (int g = 0; g < 4; g++) {
        int row = blockIdx.y * 128 + w * 32 + i * 16 + kg * 4 + g;
        part_l[(size_t)blockIdx.x * ROWPAD + row] = lsum[i][g];
      }
  }
}

// ------------------------- fc GEMM (async dbuf, K = 12800, split-K=20) -----
__global__ __launch_bounds__(256) void fc_gemm(const __bf16* __restrict__ A,
                                               const __bf16* __restrict__ Bt,
                                               float* __restrict__ part, int Mr)
{
  __shared__ __attribute__((aligned(16))) char lds[2][49152];
  int tid = threadIdx.x;
  int lane = tid & 63, wave = tid >> 6;
  int wM = wave >> 1, wN = wave & 1;
  int r = lane & 15, kg = lane >> 4;
  int rowBase = blockIdx.y * 128;
  int kbeg = blockIdx.x * (KFC / FSPLIT);   // 640
  int wbase = (tid & ~63) * 16;

  auto stage = [&](int buf, int ks) {
    int kb = kbeg + ks * 64;
    #pragma unroll
    for (int q = 0; q < 12; q++) {
      int X = q * 4096 + wbase + lane * 16;
      int row = X >> 7, off = X & 127;
      int soff = off ^ ((row & 7) << 4);
      const char* g;
      if (row < 128) {
        int grow = min(rowBase + row, Mr - 1);
        g = (const char*)A + (size_t)grow * (KFC * 2) + kb * 2 + soff;
      } else {
        g = (const char*)Bt + (size_t)(row - 128) * (KFC * 2) + kb * 2 + soff;
      }
      gload_lds16(g, lds[buf] + q * 4096 + wbase);
    }
  };

  f32x4 acc[4][8];
  #pragma unroll
  for (int i = 0; i < 4; i++)
    #pragma unroll
    for (int j = 0; j < 8; j++) {
      acc[i][j][0] = 0.f; acc[i][j][1] = 0.f; acc[i][j][2] = 0.f; acc[i][j][3] = 0.f;
    }

  constexpr int NS = KFC / FSPLIT / 64;   // 10
  stage(0, 0);
  __syncthreads();

  for (int ks = 0; ks < NS; ks++) {
    if (ks + 1 < NS) stage((ks + 1) & 1, ks + 1);   // loads in flight across MFMA
    const char* L = lds[ks & 1];
    __builtin_amdgcn_s_setprio(1);
    #pragma unroll
    for (int kf = 0; kf < 2; kf++) {
      bf16x8 a[4], b[8];
      #pragma unroll
      for (int i = 0; i < 4; i++) {
        int row = wM * 64 + i * 16 + r;
        int off = (kf * 64 + kg * 16) ^ ((row & 7) << 4);
        a[i] = *(const bf16x8*)(L + row * 128 + off);
      }
      #pragma unroll
      for (int j = 0; j < 8; j++) {
        int row = 128 + wN * 128 + j * 16 + r;
        int off = (kf * 64 + kg * 16) ^ ((row & 7) << 4);
        b[j] = *(const bf16x8*)(L + row * 128 + off);
      }
      #pragma unroll
      for (int i = 0; i < 4; i++)
        #pragma unroll
        for (int j = 0; j < 8; j++)
          acc[i][j] = mfma16(a[i], b[j], acc[i][j]);
    }
    __builtin_amdgcn_s_setprio(0);
    __syncthreads();   // drains prefetch (vmcnt) + all waves done with L
  }

  float* pz = part + (size_t)blockIdx.x * Mr * H;
  #pragma unroll
  for (int i = 0; i < 4; i++)
    #pragma unroll
    for (int g = 0; g < 4; g++) {
      int row = rowBase + wM * 64 + i * 16 + kg * 4 + g;
      if (row >= Mr) continue;
      #pragma unroll
      for (int j = 0; j < 8; j++) {
        int col = wN * 128 + j * 16 + r;
        pz[(size_t)row * H + col] = acc[i][j][g];
      }
    }
}

// ------------------------- GRU dual GEMM (z=0: gi, z=1: gh) ----------------
__global__ void gru_gemm2_k(const __bf16* __restrict__ xinb, const __bf16* __restrict__ relb,
                            const __bf16* __restrict__ Wihb, const __bf16* __restrict__ Whhb,
                            const float* __restrict__ b_ih, const float* __restrict__ b_hh,
                            float* __restrict__ gi, float* __restrict__ gh)
{
  const __bf16* A; const __bf16* Bt; const float* bias; float* C; int K;
  if (blockIdx.z == 0) { A = xinb; Bt = Wihb; bias = b_ih; C = gi; K = 2 * H; }
  else                 { A = relb; Bt = Whhb; bias = b_hh; C = gh; K = H; }
  const int Mr = R2, N = H3;

  int lane = threadIdx.x & 63, wave = threadIdx.x >> 6;
  int waveM = wave >> 1, waveN = wave & 1;
  int r = lane & 15, kg = lane >> 4;
  int rowBase = blockIdx.y * 64 + waveM * 32;
  int colBase = blockIdx.x * 64 + waveN * 32;

  int row0 = rowBase + r, row1 = rowBase + 16 + r;
  int col0 = colBase + r, col1 = colBase + 16 + r;
  bool v0 = row0 < Mr, v1 = row1 < Mr;
  const __bf16* a0p = A + (size_t)row0 * K + kg * 8;
  const __bf16* a1p = A + (size_t)row1 * K + kg * 8;
  const __bf16* b0p = Bt + (size_t)col0 * K + kg * 8;
  const __bf16* b1p = Bt + (size_t)col1 * K + kg * 8;

  f32x4 acc[2][2];
  #pragma unroll
  for (int i = 0; i < 2; i++)
    #pragma unroll
    for (int j = 0; j < 2; j++) { acc[i][j][0] = 0.f; acc[i][j][1] = 0.f; acc[i][j][2] = 0.f; acc[i][j][3] = 0.f; }

  for (int k0 = 0; k0 < K; k0 += 32) {
    bf16x8 a0 = v0 ? ldb8(a0p + k0) : zerob8();
    bf16x8 a1 = v1 ? ldb8(a1p + k0) : zerob8();
    bf16x8 b0 = ldb8(b0p + k0);
    bf16x8 b1 = ldb8(b1p + k0);
    acc[0][0] = mfma16(a0, b0, acc[0][0]);
    acc[0][1] = mfma16(a0, b1, acc[0][1]);
    acc[1][0] = mfma16(a1, b0, acc[1][0]);
    acc[1][1] = mfma16(a1, b1, acc[1][1]);
  }

  #pragma unroll
  for (int i = 0; i < 2; i++) {
    #pragma unroll
    for (int g = 0; g < 4; g++) {
      int row = rowBase + i * 16 + kg * 4 + g;
      if (row >= Mr) continue;
      #pragma unroll
      for (int j = 0; j < 2; j++) {
        int col = colBase + j * 16 + r;
        C[(size_t)row * N + col] = acc[i][j][g] + bias[col];
      }
    }
  }
}

// sum split-K partials + bias + relu -> q (fp32) and qb (bf16, prescaled log2 e)
__global__ void fc_reduce(const float* __restrict__ part, const float* __restrict__ bias,
                          float* __restrict__ q, __bf16* __restrict__ qb, int nrows)
{
  int idx = blockIdx.x * 256 + threadIdx.x;       // nrows * H
  if (idx >= nrows * H) return;
  int col = idx & 255;
  float s = bias[col];
  for (int z = 0; z < FSPLIT; z++) s += part[(size_t)z * nrows * H + idx];
  s = fmaxf(s, 0.f);
  q[idx] = s;
  qb[idx] = (__bf16)(s * 1.44269504f);
}

// ------------------------- conv (block per test row) -----------------------
__global__ void conv_feat(const float* __restrict__ ent, const float* __restrict__ rel,
                          const float* __restrict__ sent, const int* __restrict__ tt,
                          const float* __restrict__ cw, const float* __restrict__ cb,
                          __bf16* __restrict__ out, int row0)
{
  __shared__ float f[3][258];
  __shared__ float wsm[CH * 9];
  __shared__ float bsm[CH];
  int i = row0 + blockIdx.x;
  int h = threadIdx.x;
  int j = (i < NT) ? i : i - NT;
  int a0 = (i < NT) ? tt[j * 3 + 0] : tt[j * 3 + 2];
  int a1 = (i < NT) ? tt[j * 3 + 1] : tt[j * 3 + 1] + NR;
  f[0][h + 1] = ent[(size_t)a0 * H + h];
  f[1][h + 1] = rel[(size_t)a1 * H + h];
  f[2][h + 1] = sent[(size_t)j * H + h];
  if (h < 3) { f[h][0] = 0.f; f[h][257] = 0.f; }
  for (int x = h; x < CH * 9; x += 256) wsm[x] = cw[x];
  if (h < CH) bsm[h] = cb[h];
  __syncthreads();
  __bf16* orow = out + (size_t)blockIdx.x * KFC;
  for (int c = 0; c < CH; c++) {
    const float* wc = wsm + c * 9;
    float s = bsm[c];
    #pragma unroll
    for (int ic = 0; ic < 3; ic++)
      s += wc[ic * 3 + 0] * f[ic][h] + wc[ic * 3 + 1] * f[ic][h + 1] + wc[ic * 3 + 2] * f[ic][h + 2];
    orow[(size_t)c * H + h] = (__bf16)fmaxf(s, 0.f);
  }
}

// one wave per row: nll[row] = log(sum_c part_l - PADCOLS) - q[row].ent[tgt]
__global__ void lse_combine(const float* __restrict__ part_l, const float* __restrict__ qf,
                            const float* __restrict__ ent, const int* __restrict__ tt,
                            float* __restrict__ nll)
{
  int gid = blockIdx.x * 256 + threadIdx.x;
  int w = gid >> 6;
  if (w >= NT2) return;
  int lane = gid & 63;
  int j = (w < NT) ? w : w - NT;
  int tgt = (w < NT) ? tt[j * 3 + 2] : tt[j * 3 + 0];
  const float4 qa = ((const float4*)(qf + (size_t)w * H))[lane];
  const float4 ea = ((const float4*)(ent + (size_t)tgt * H))[lane];
  float d = qa.x * ea.x + qa.y * ea.y + qa.z * ea.z + qa.w * ea.w;
  float s = (lane < NCHUNK) ? part_l[(size_t)lane * ROWPAD + w] : 0.f;
  #pragma unroll
  for (int o = 32; o > 0; o >>= 1) {
    d += __shfl_down(d, o, 64);
    s += __shfl_down(s, o, 64);
  }
  if (lane == 0) nll[w] = logf(s - PADCOLS) - d;
}

__global__ void mean_nll(const float* __restrict__ nll, float* __restrict__ out)
{
  float s = 0.f;
  for (int i = threadIdx.x; i < NT2; i += 256) s += nll[i];
  s = block_sum256(s);
  if (threadIdx.x == 0) out[0] = s * (1.f / NT2);
}

// ------------------------- launcher ----------------------------------------
extern "C" void kernel_launch(void* const* d_in, const int* in_sizes, int n_in,
                              void* d_out, int out_size, void* d_ws, size_t ws_size,
                              hipStream_t stream)
{
  const float* dynamic_emb = (const float*)d_in[0];
  const float* emb_rel     = (const float*)d_in[1];
  const float* gru_W_ih    = (const float*)d_in[2];
  const float* gru_W_hh    = (const float*)d_in[3];
  const float* gru_b_ih    = (const float*)d_in[4];
  const float* gru_b_hh    = (const float*)d_in[5];
  const float* agg_W       = (const float*)d_in[6];
  const float* tg_W        = (const float*)d_in[7];
  const float* tg_b        = (const float*)d_in[8];
  const float* hev         = (const float*)d_in[9];
  const float* hrv         = (const float*)d_in[10];
  const float* conv_w      = (const float*)d_in[11];
  const float* conv_b      = (const float*)d_in[12];
  const float* fc_W        = (const float*)d_in[13];
  const float* fc_b        = (const float*)d_in[14];
  const float* sent        = (const float*)d_in[15];
  const int* edge_src = (const int*)d_in[16];
  const int* edge_rel = (const int*)d_in[17];
  const int* edge_dst = (const int*)d_in[18];
  const int* r_to_e   = (const int*)d_in[19];
  const int* r_ids    = (const int*)d_in[20];
  const int* he_row   = (const int*)d_in[21];
  const int* he_col   = (const int*)d_in[22];
  const int* hr_row   = (const int*)d_in[23];
  const int* hr_col   = (const int*)d_in[24];
  const int* tt       = (const int*)d_in[25];
  float* out = (float*)d_out;

  char* base = (char*)d_ws;
  size_t off = 0;
  auto alloc = [&](size_t bytes) { char* p = base + off; off += (bytes + 255) & ~(size_t)255; return p; };

  float* ent    = (float*)alloc((size_t)NE * H * 4);
  float* curr   = (float*)alloc((size_t)NE * H * 4);   // hyper ping-pong; conv_bf overlay
  float* tgbuf  = (float*)alloc((size_t)NE * H * 4);
  __bf16* convb = (__bf16*)curr;                        // 1600*12800*2 = 40.96 MB spans curr+tgbuf
  __bf16* entb  = (__bf16*)alloc((size_t)NE * H * 2);
  __bf16* entb2 = (__bf16*)alloc((size_t)NE * H * 2);
  __bf16* accEb = (__bf16*)alloc((size_t)NE * H * 2);
  __bf16* ebf   = (__bf16*)alloc((size_t)NEPAD * H * 2);   // frag-packed ent
  __bf16* qbf   = (__bf16*)alloc((size_t)ROWPAD * H * 2);  // frag-packed q
  float* rel    = (float*)alloc((size_t)R2 * H * 4);
  float* accR   = (float*)alloc((size_t)R2 * H * 4);
  __bf16* relb  = (__bf16*)alloc((size_t)R2 * H * 2);
  __bf16* xinb  = (__bf16*)alloc((size_t)R2 * 2 * H * 2);
  float* gi     = (float*)alloc((size_t)R2 * H3 * 4);
  float* gh     = (float*)alloc((size_t)R2 * H3 * 4);
  float* qf     = (float*)alloc((size_t)NT2 * H * 4);
  __bf16* qb    = (__bf16*)alloc((size_t)NT2 * H * 2);
  float* part_l = (float*)alloc((size_t)NCHUNK * ROWPAD * 4);
  float* partM  = (float*)alloc((size_t)R2 * MSPLIT * H * 4);
  float* fcpart = (float*)alloc((size_t)FSPLIT * 1600 * H * 4);   // 32.8 MB
  float* nll    = (float*)alloc((size_t)NT2 * 4);
  __bf16* tgWtb = (__bf16*)alloc((size_t)H * H * 2);
  __bf16* aggWtb= (__bf16*)alloc((size_t)H * H * 2);
  __bf16* fcWtb = (__bf16*)alloc((size_t)H * KFC * 2);
  __bf16* Wihb  = (__bf16*)alloc((size_t)H3 * 2 * H * 2);
  __bf16* Whhb  = (__bf16*)alloc((size_t)H3 * H * 2);

  int* ip = (int*)alloc(0);
  size_t ioff = 0;
  auto ialloc = [&](size_t n) { int* p = ip + ioff; ioff += n; return p; };
  int* fidxM[TT];
  int2* fsrE[TT];
  for (int t = 0; t < TT; t++) fidxM[t] = ialloc(M);
  for (int t = 0; t < TT; t++) fsrE[t] = (int2*)ialloc((size_t)NEDGE * 2);
  int2* fcvHE = (int2*)ialloc((size_t)NNZ_E * 2);
  int2* fcvHR = (int2*)ialloc((size_t)NNZ_R * 2);
  int* cnt_all    = ialloc(CNT_TOTAL);
  int* start_all  = ialloc(CNT_TOTAL);
  int* cursor_all = ialloc(CNT_TOTAL);
  int* bcnt  = ialloc((size_t)4 * NB_CS * 512);
  int* bbase = ialloc((size_t)4 * NB_CS * 512);
  int* bsumNE = ialloc((size_t)4 * NB_NE);

  int* sM[TT];  for (int t = 0; t < TT; t++) sM[t] = start_all + t * 512;
  int* sHR = start_all + 1536;
  int* sE[TT];  for (int t = 0; t < TT; t++) sE[t] = start_all + CNT_NE_BASE + t * CNT_NE_STRIDE;
  int* sHE = start_all + CNT_NE_BASE + 3 * CNT_NE_STRIDE;

  // --- weight prep (bf16) ---
  transpose_cast_k<<<dim3(H / 32, H / 32), 256, 0, stream>>>(tg_W, tgWtb, H, H);
  transpose_cast_k<<<dim3(H / 32, H / 32), 256, 0, stream>>>(agg_W, aggWtb, H, H);
  transpose_cast_k<<<dim3(KFC / 32, H / 32), 256, 0, stream>>>(fc_W, fcWtb, KFC, H);
  cast_bf16_k<<<(H3 * 2 * H / 8 + 255) / 256, 256, 0, stream>>>(gru_W_ih, Wihb, H3 * 2 * H / 8);
  cast_bf16_k<<<(H3 * H / 8 + 255) / 256, 256, 0, stream>>>(gru_W_hh, Whhb, H3 * H / 8);

  // --- CSR build: counting-sort for R2-keyed arrays ---
  cs_hist_k<<<dim3(NB_CS, 4), 256, 0, stream>>>(r_ids, hr_row, bcnt);
  cs_scan_k<<<4, 256, 0, stream>>>(bcnt, bbase, start_all);
  cs_scatter_k<<<dim3(NB_CS, 4), 256, 0, stream>>>(r_ids, r_to_e, hr_row, hr_col, hrv, bbase,
                                                   fidxM[0], fidxM[1], fidxM[2], fcvHR);

  // --- CSR build: NE-keyed arrays (parallel 3-phase scan) ---
  hipMemsetAsync(cnt_all + CNT_NE_BASE, 0, (size_t)(CNT_TOTAL - CNT_NE_BASE) * 4, stream);
  hist_ne_k<<<dim3((NNZ_E + 255) / 256, 4), 256, 0, stream>>>(edge_dst, he_row, cnt_all);
  scan_ne1_k<<<dim3(NB_NE, 4), 256, 0, stream>>>(cnt_all, start_all, bsumNE);
  scan_ne2_k<<<4, 256, 0, stream>>>(bsumNE, start_all);
  scan_ne3_k<<<dim3(NB_NE, 4), 256, 0, stream>>>(start_all, cursor_all, bsumNE);
  perm_fuse2i_k<<<dim3((NEDGE + 255) / 256, 3), 256, 0, stream>>>(
      edge_dst, edge_src, edge_rel, cursor_all, fsrE[0], fsrE[1], fsrE[2]);
  perm_fusevi_k<<<(NNZ_E + 255) / 256, 256, 0, stream>>>(
      he_row, he_col, hev, NNZ_E, cursor_all + CNT_NE_BASE + 3 * CNT_NE_STRIDE, fcvHE);

  constexpr int NEH8 = NE * H / 8, R2H8 = R2 * H / 8;
  constexpr int NE_RB = (NE + 127) / 128;   // 157

  // fused copy + bf16 cast
  copy_cast_k<<<(NEH8 + 255) / 256, 256, 0, stream>>>(dynamic_emb, ent, entb, NEH8);
  copy_cast_k<<<(R2H8 + 255) / 256, 256, 0, stream>>>(emb_rel, rel, relb, R2H8);

  for (int t = 0; t < TT; t++) {
    // --- rel update (GRU) ---
    gather_mean2_k<<<dim3(R2, MSPLIT), 256, 0, stream>>>(entb, fidxM[t], sM[t], partM);
    mean_xin_k<<<R2, 256, 0, stream>>>(partM, sM[t], rel, xinb);
    gru_gemm2_k<<<dim3(H3 / 64, (R2 + 63) / 64, 2), 256, 0, stream>>>(
        xinb, relb, Wihb, Whhb, gru_b_ih, gru_b_hh, gi, gh);
    gru_combine<<<(R2 * H + 255) / 256, 256, 0, stream>>>(gi, gh, rel, relb);

    // --- ent update: gate, gather, agg+blend (fused) ---
    panel2_gemm<2><<<dim3(4, NE_RB), 256, 0, stream>>>(
        entb, tgWtb, tg_b, tgbuf, NE, H, nullptr, nullptr, nullptr);
    gather_edges3_k<<<NE, 256, 0, stream>>>(entb, relb, fsrE[t], sE[t], accEb);
    panel2_gemm<4><<<dim3(4, NE_RB), 256, 0, stream>>>(
        accEb, aggWtb, nullptr, nullptr, NE, H, tgbuf, ent, entb);
  }

  // --- hypergraph layers ---
  hyper3_k<<<NE, 256, 0, stream>>>(ent, entb, fcvHE, sHE, curr, entb2);
  hyper3_k<<<NE, 256, 0, stream>>>(curr, entb2, fcvHE, sHE, ent, entb);
  hyper_rel_k<<<R2, 256, 0, stream>>>(rel, fcvHR, sHR, accR);
  hyper_rel_k<<<R2, 256, 0, stream>>>(accR, fcvHR, sHR, rel);

  // frag-pack final ent for scores B
  pack_frag_k<<<(NEPAD * 32 + 255) / 256, 256, 0, stream>>>(entb, ebf, NEPAD * 32, NE);

  // --- conv + fc (3 chunks: 1600, 1600, 800 rows) ---
  for (int c = 0; c < 3; c++) {
    int row0 = c * 1600;
    int rows = min(1600, NT2 - row0);
    conv_feat<<<rows, 256, 0, stream>>>(ent, rel, sent, tt, conv_w, conv_b, convb, row0);
    fc_gemm<<<dim3(FSPLIT, (rows + 127) / 128), 256, 0, stream>>>(convb, fcWtb, fcpart, rows);
    fc_reduce<<<(rows * H + 255) / 256, 256, 0, stream>>>(
        fcpart, fc_b, qf + (size_t)row0 * H, qb + (size_t)row0 * H, rows);
  }

  // frag-pack q for scores A
  pack_frag_k<<<(ROWPAD * 32 + 255) / 256, 256, 0, stream>>>(qb, qbf, ROWPAD * 32, NT2);

  // --- fused scores + LSE: 32 chunks x 32 row-blocks, 20 panels each ---
  scores_v4<<<dim3(NCHUNK, 32), 256, 0, stream>>>(qbf, ebf, part_l);
  lse_combine<<<(NT2 * 64 + 255) / 256, 256, 0, stream>>>(part_l, qf, ent, tt, nll);
  mean_nll<<<1, 256, 0, stream>>>(nll, out);
}